// Round 2
// baseline (1928.094 us; speedup 1.0000x reference)
//
#include <hip/hip_runtime.h>

#define BB 2
#define TT 1024
#define DD 768
#define HH 12
#define HD 64
#define FFD 3072
#define NE 4
#define NTOK (BB*TT)

// ---------------------------------------------------------------------------
// Y[MxN] = A[MxK](f32) * B[NxK]^T(f32) + bias
// mode 0: scatter fp32 to [B,H,T,64] (QKV).  mode 1: outF = y + src (residual).
// ---------------------------------------------------------------------------
__global__ __launch_bounds__(256) void gemm_nt_kernel(
    const float* __restrict__ A, const float* __restrict__ Bm,
    const float* __restrict__ bias, int M, int N, int K,
    int mode, float* __restrict__ outF, const float* __restrict__ src)
{
    __shared__ float As[32][68];
    __shared__ float Bs[32][68];
    const int tid = threadIdx.x;
    const int m0 = blockIdx.y * 64, n0 = blockIdx.x * 64;
    const int ty = tid >> 4, tx = tid & 15;
    const int lrow = tid >> 2, lcol = (tid & 3) * 8;
    float acc[4][4] = {};
    for (int k0 = 0; k0 < K; k0 += 32) {
        const float* ap = A + (size_t)(m0 + lrow) * K + k0 + lcol;
        const float* bp = Bm + (size_t)(n0 + lrow) * K + k0 + lcol;
        float4 a0 = *reinterpret_cast<const float4*>(ap);
        float4 a1 = *reinterpret_cast<const float4*>(ap + 4);
        float4 b0 = *reinterpret_cast<const float4*>(bp);
        float4 b1 = *reinterpret_cast<const float4*>(bp + 4);
        float fa[8] = {a0.x, a0.y, a0.z, a0.w, a1.x, a1.y, a1.z, a1.w};
        float fb[8] = {b0.x, b0.y, b0.z, b0.w, b1.x, b1.y, b1.z, b1.w};
        #pragma unroll
        for (int j = 0; j < 8; j++) { As[lcol + j][lrow] = fa[j]; Bs[lcol + j][lrow] = fb[j]; }
        __syncthreads();
        #pragma unroll
        for (int kk = 0; kk < 32; kk++) {
            float4 a4 = *reinterpret_cast<const float4*>(&As[kk][ty * 4]);
            float4 b4 = *reinterpret_cast<const float4*>(&Bs[kk][tx * 4]);
            float av[4] = {a4.x, a4.y, a4.z, a4.w};
            float bv[4] = {b4.x, b4.y, b4.z, b4.w};
            #pragma unroll
            for (int i = 0; i < 4; i++)
                #pragma unroll
                for (int j = 0; j < 4; j++)
                    acc[i][j] = fmaf(av[i], bv[j], acc[i][j]);
        }
        __syncthreads();
    }
    #pragma unroll
    for (int i = 0; i < 4; i++) {
        int m = m0 + ty * 4 + i;
        #pragma unroll
        for (int j = 0; j < 4; j++) {
            int n = n0 + tx * 4 + j;
            float y = acc[i][j] + bias[n];
            if (mode == 0) {
                int bb = m / TT, t = m % TT, hh = n >> 6, dd = n & 63;
                outF[(((size_t)(bb * HH + hh) * TT + t) << 6) + dd] = y;
            } else {
                size_t idx = (size_t)m * N + n;
                outF[idx] = y + src[idx];
            }
        }
    }
}

// ---------------------------------------------------------------------------
// Y[MxN] = A[MxK](f32) * B[KxN](f32) + bias
// mode 0: outY = relu(y).  mode 1: outY += comb[m*NE+eidx] * y.
// ---------------------------------------------------------------------------
__global__ __launch_bounds__(256) void gemm_nn_kernel(
    const float* __restrict__ A, const float* __restrict__ Bm,
    const float* __restrict__ bias, int M, int N, int K, int mode,
    float* __restrict__ outY, const float* __restrict__ comb, int eidx)
{
    __shared__ float As[32][68];
    __shared__ float Bs[32][68];
    const int tid = threadIdx.x;
    const int m0 = blockIdx.y * 64, n0 = blockIdx.x * 64;
    const int ty = tid >> 4, tx = tid & 15;
    const int arow = tid >> 2, acol = (tid & 3) * 8;
    const int brow = tid >> 3, bcol = (tid & 7) * 8;
    float acc[4][4] = {};
    for (int k0 = 0; k0 < K; k0 += 32) {
        const float* ap = A + (size_t)(m0 + arow) * K + k0 + acol;
        const float* bp = Bm + (size_t)(k0 + brow) * N + n0 + bcol;
        float4 a0 = *reinterpret_cast<const float4*>(ap);
        float4 a1 = *reinterpret_cast<const float4*>(ap + 4);
        float4 b0 = *reinterpret_cast<const float4*>(bp);
        float4 b1 = *reinterpret_cast<const float4*>(bp + 4);
        float fa[8] = {a0.x, a0.y, a0.z, a0.w, a1.x, a1.y, a1.z, a1.w};
        float fb[8] = {b0.x, b0.y, b0.z, b0.w, b1.x, b1.y, b1.z, b1.w};
        #pragma unroll
        for (int j = 0; j < 8; j++) { As[acol + j][arow] = fa[j]; Bs[brow][bcol + j] = fb[j]; }
        __syncthreads();
        #pragma unroll
        for (int kk = 0; kk < 32; kk++) {
            float4 a4 = *reinterpret_cast<const float4*>(&As[kk][ty * 4]);
            float4 b4 = *reinterpret_cast<const float4*>(&Bs[kk][tx * 4]);
            float av[4] = {a4.x, a4.y, a4.z, a4.w};
            float bv[4] = {b4.x, b4.y, b4.z, b4.w};
            #pragma unroll
            for (int i = 0; i < 4; i++)
                #pragma unroll
                for (int j = 0; j < 4; j++)
                    acc[i][j] = fmaf(av[i], bv[j], acc[i][j]);
        }
        __syncthreads();
    }
    #pragma unroll
    for (int i = 0; i < 4; i++) {
        int m = m0 + ty * 4 + i;
        #pragma unroll
        for (int j = 0; j < 4; j++) {
            int n = n0 + tx * 4 + j;
            float y = acc[i][j] + bias[n];
            size_t idx = (size_t)m * N + n;
            if (mode == 0) {
                outY[idx] = fmaxf(y, 0.f);
            } else {
                outY[idx] += comb[m * NE + eidx] * y;
            }
        }
    }
}

// ---------------------------------------------------------------------------
// Attention: per block = (b, h, 32 q-rows). Two passes over K.
// probs = softmax(a*l), a = gamma/(std_ddof1(l)+1e-5); shift cancels in softmax.
// ---------------------------------------------------------------------------
__global__ __launch_bounds__(256) void attn_kernel(
    const float* __restrict__ Qb, const float* __restrict__ Kb,
    const float* __restrict__ Vb, const float* __restrict__ gamma_p,
    float* __restrict__ attn_out)
{
    const int qt = blockIdx.x, h = blockIdx.y, b = blockIdx.z;
    __shared__ float Qs[32][68];
    __shared__ float Ks[64][68];
    __shared__ float Vs[64][68];
    __shared__ float Ps[32][68];
    __shared__ float aArr[32], cmArr[32], dArr[32];
    const int tid = threadIdx.x;
    const float scale = 0.125f;  // hd^-0.5
    const float gamma = gamma_p[0];
    const float* Qh = Qb + (size_t)(b * HH + h) * TT * HD;
    const float* Kh = Kb + (size_t)(b * HH + h) * TT * HD;
    const float* Vh = Vb + (size_t)(b * HH + h) * TT * HD;
    const int m0 = qt * 32;

    for (int i = tid; i < 32 * 64; i += 256) {
        int r = i >> 6, c = i & 63;
        Qs[r][c] = Qh[(size_t)(m0 + r) * HD + c] * scale;
    }
    __syncthreads();

    const int q = tid >> 3, l = tid & 7;
    float s1 = 0.f, s2 = 0.f, mx = -1e30f, mn = 1e30f;
    for (int kt = 0; kt < TT; kt += 64) {
        for (int i = tid; i < 64 * 64; i += 256) {
            int r = i >> 6, c = i & 63;
            Ks[r][c] = Kh[(size_t)(kt + r) * HD + c];
        }
        __syncthreads();
        for (int kk = l; kk < 64; kk += 8) {
            float lv = 0.f;
            #pragma unroll
            for (int d4 = 0; d4 < 16; d4++) {
                float4 qa = *reinterpret_cast<const float4*>(&Qs[q][d4 * 4]);
                float4 ka = *reinterpret_cast<const float4*>(&Ks[kk][d4 * 4]);
                lv = fmaf(qa.x, ka.x, lv); lv = fmaf(qa.y, ka.y, lv);
                lv = fmaf(qa.z, ka.z, lv); lv = fmaf(qa.w, ka.w, lv);
            }
            s1 += lv; s2 += lv * lv;
            mx = fmaxf(mx, lv); mn = fminf(mn, lv);
        }
        __syncthreads();
    }
    #pragma unroll
    for (int off = 4; off > 0; off >>= 1) {
        s1 += __shfl_down(s1, off, 8);
        s2 += __shfl_down(s2, off, 8);
        mx = fmaxf(mx, __shfl_down(mx, off, 8));
        mn = fminf(mn, __shfl_down(mn, off, 8));
    }
    if (l == 0) {
        float var = (s2 - s1 * s1 / (float)TT) / (float)(TT - 1);
        var = fmaxf(var, 0.f);
        float a = gamma / (sqrtf(var) + 1e-5f);
        aArr[q] = a;
        cmArr[q] = (a >= 0.f) ? a * mx : a * mn;
    }
    __syncthreads();
    const float a = aArr[q], cm = cmArr[q];
    float dpart = 0.f;
    float Oacc[8] = {};
    for (int kt = 0; kt < TT; kt += 64) {
        for (int i = tid; i < 64 * 64; i += 256) {
            int r = i >> 6, c = i & 63;
            Ks[r][c] = Kh[(size_t)(kt + r) * HD + c];
            Vs[r][c] = Vh[(size_t)(kt + r) * HD + c];
        }
        __syncthreads();
        for (int kk = l; kk < 64; kk += 8) {
            float lv = 0.f;
            #pragma unroll
            for (int d4 = 0; d4 < 16; d4++) {
                float4 qa = *reinterpret_cast<const float4*>(&Qs[q][d4 * 4]);
                float4 ka = *reinterpret_cast<const float4*>(&Ks[kk][d4 * 4]);
                lv = fmaf(qa.x, ka.x, lv); lv = fmaf(qa.y, ka.y, lv);
                lv = fmaf(qa.z, ka.z, lv); lv = fmaf(qa.w, ka.w, lv);
            }
            float p = __expf(a * lv - cm);
            Ps[q][kk] = p;
            dpart += p;
        }
        __syncthreads();
        for (int kk = 0; kk < 64; kk++) {
            float p = Ps[q][kk];
            #pragma unroll
            for (int j = 0; j < 8; j++) Oacc[j] += p * Vs[kk][l * 8 + j];
        }
        __syncthreads();
    }
    #pragma unroll
    for (int off = 4; off > 0; off >>= 1) dpart += __shfl_down(dpart, off, 8);
    if (l == 0) dArr[q] = dpart;
    __syncthreads();
    const float dinv = 1.f / dArr[q];
    const int t = m0 + q;
    float* orow = attn_out + ((size_t)(b * TT + t)) * DD + h * HD + l * 8;
    #pragma unroll
    for (int j = 0; j < 8; j++) orow[j] = Oacc[j] * dinv;
}

// ---------------------------------------------------------------------------
// LayerNorm over D=768. mode 0: in1 -> outF. mode 1: in1+in2 -> outF.
// ---------------------------------------------------------------------------
__global__ __launch_bounds__(256) void ln_kernel(
    const float* __restrict__ in1, const float* __restrict__ in2,
    const float* __restrict__ g, const float* __restrict__ bta,
    float* __restrict__ outF, int mode)
{
    const int row = blockIdx.x, tid = threadIdx.x;
    __shared__ float red[256];
    const size_t base = (size_t)row * DD;
    float v[3];
    #pragma unroll
    for (int i = 0; i < 3; i++) {
        int c = tid + i * 256;
        float t = in1[base + c];
        if (mode == 1) t += in2[base + c];
        v[i] = t;
    }
    float s = v[0] + v[1] + v[2];
    red[tid] = s; __syncthreads();
    #pragma unroll
    for (int o = 128; o > 0; o >>= 1) { if (tid < o) red[tid] += red[tid + o]; __syncthreads(); }
    const float mean = red[0] * (1.f / 768.f);
    __syncthreads();
    float qv = 0.f;
    #pragma unroll
    for (int i = 0; i < 3; i++) { float d = v[i] - mean; qv += d * d; }
    red[tid] = qv; __syncthreads();
    #pragma unroll
    for (int o = 128; o > 0; o >>= 1) { if (tid < o) red[tid] += red[tid + o]; __syncthreads(); }
    const float var = red[0] * (1.f / 768.f);
    const float rs = rsqrtf(var + 1e-5f);
    #pragma unroll
    for (int i = 0; i < 3; i++) {
        int c = tid + i * 256;
        outF[base + c] = (v[i] - mean) * rs * g[c] + bta[c];
    }
}

// ---------------------------------------------------------------------------
// Gate: one wave per token. softmax over E=4, top-2 -> combine weights.
// ---------------------------------------------------------------------------
__global__ __launch_bounds__(256) void gate_kernel(
    const float* __restrict__ x, const float* __restrict__ Wg,
    const float* __restrict__ bg, float* __restrict__ comb)
{
    const int wid = threadIdx.x >> 6, lane = threadIdx.x & 63;
    const int t = blockIdx.x * 4 + wid;
    const float* xr = x + (size_t)t * DD;
    float g[NE];
    #pragma unroll
    for (int e = 0; e < NE; e++) {
        float p = 0.f;
        for (int d = lane; d < DD; d += 64) p += xr[d] * Wg[e * DD + d];
        #pragma unroll
        for (int off = 32; off > 0; off >>= 1) p += __shfl_down(p, off, 64);
        g[e] = p;
    }
    if (lane == 0) {
        float m = -1e30f;
        #pragma unroll
        for (int e = 0; e < NE; e++) { g[e] += bg[e]; m = fmaxf(m, g[e]); }
        float ex[NE], s = 0.f;
        #pragma unroll
        for (int e = 0; e < NE; e++) { ex[e] = __expf(g[e] - m); s += ex[e]; }
        #pragma unroll
        for (int e = 0; e < NE; e++) ex[e] /= s;
        int e1 = 0;
        #pragma unroll
        for (int e = 1; e < NE; e++) if (ex[e] > ex[e1]) e1 = e;
        int e2 = -1;
        #pragma unroll
        for (int e = 0; e < NE; e++) if (e != e1 && (e2 < 0 || ex[e] > ex[e2])) e2 = e;
        float c[NE] = {0.f, 0.f, 0.f, 0.f};
        c[e1] = ex[e1]; c[e2] = ex[e2];
        #pragma unroll
        for (int e = 0; e < NE; e++) comb[(size_t)t * NE + e] = c[e];
    }
}

__global__ __launch_bounds__(256) void zero_kernel(float* __restrict__ p, int n)
{
    int i = blockIdx.x * 256 + threadIdx.x;
    if (i < n) p[i] = 0.f;
}

extern "C" void kernel_launch(void* const* d_in, const int* in_sizes, int n_in,
                              void* d_out, int out_size, void* d_ws, size_t ws_size,
                              hipStream_t stream)
{
    const float* src  = (const float*)d_in[0];
    const float* Wq   = (const float*)d_in[2];  const float* bq = (const float*)d_in[3];
    const float* Wk   = (const float*)d_in[4];  const float* bk = (const float*)d_in[5];
    const float* Wv   = (const float*)d_in[6];  const float* bv = (const float*)d_in[7];
    const float* Wo   = (const float*)d_in[8];  const float* bo = (const float*)d_in[9];
    const float* gam  = (const float*)d_in[10];
    const float* ln1g = (const float*)d_in[11]; const float* ln1b = (const float*)d_in[12];
    const float* ln2g = (const float*)d_in[13]; const float* ln2b = (const float*)d_in[14];
    const float* Wg   = (const float*)d_in[15]; const float* bg = (const float*)d_in[16];
    const float* W1   = (const float*)d_in[17]; const float* b1 = (const float*)d_in[18];
    const float* W2   = (const float*)d_in[19]; const float* b2 = (const float*)d_in[20];

    char* ws = (char*)d_ws;
    size_t off = 0;
    auto alloc = [&](size_t bytes) -> void* {
        void* p = ws + off;
        off += (bytes + 255) & ~(size_t)255;
        return p;
    };
    float* Qb     = (float*)alloc(sizeof(float) * BB * HH * TT * HD);   // aliased by r1
    float* Kb     = (float*)alloc(sizeof(float) * BB * HH * TT * HD);   // aliased by x
    float* Vb     = (float*)alloc(sizeof(float) * BB * HH * TT * HD);   // aliased by ff
    float* attn_f = (float*)alloc(sizeof(float) * NTOK * DD);
    float* comb   = (float*)alloc(sizeof(float) * NTOK * NE);
    float* hb     = (float*)alloc(sizeof(float) * NTOK * FFD);
    // aliases (lifetimes verified: Q/K/V dead by the time these live)
    float* r1 = Qb;
    float* x  = Kb;
    float* ff = Vb;
    (void)ws_size; (void)in_sizes; (void)n_in; (void)out_size;

    dim3 gProj(DD / 64, NTOK / 64);
    gemm_nt_kernel<<<gProj, 256, 0, stream>>>(src, Wq, bq, NTOK, DD, DD, 0, Qb, nullptr);
    gemm_nt_kernel<<<gProj, 256, 0, stream>>>(src, Wk, bk, NTOK, DD, DD, 0, Kb, nullptr);
    gemm_nt_kernel<<<gProj, 256, 0, stream>>>(src, Wv, bv, NTOK, DD, DD, 0, Vb, nullptr);

    attn_kernel<<<dim3(TT / 32, HH, BB), 256, 0, stream>>>(Qb, Kb, Vb, gam, attn_f);

    gemm_nt_kernel<<<gProj, 256, 0, stream>>>(attn_f, Wo, bo, NTOK, DD, DD, 1, r1, src);

    ln_kernel<<<NTOK, 256, 0, stream>>>(r1, nullptr, ln1g, ln1b, x, 0);

    gate_kernel<<<NTOK / 4, 256, 0, stream>>>(x, Wg, bg, comb);
    zero_kernel<<<(NTOK * DD + 255) / 256, 256, 0, stream>>>(ff, NTOK * DD);

    for (int e = 0; e < NE; e++) {
        gemm_nn_kernel<<<dim3(FFD / 64, NTOK / 64), 256, 0, stream>>>(
            x, W1 + (size_t)e * DD * FFD, b1 + (size_t)e * FFD,
            NTOK, FFD, DD, 0, hb, nullptr, 0);
        gemm_nn_kernel<<<dim3(DD / 64, NTOK / 64), 256, 0, stream>>>(
            hb, W2 + (size_t)e * FFD * DD, b2 + (size_t)e * DD,
            NTOK, DD, FFD, 1, ff, comb, e);
    }

    ln_kernel<<<NTOK, 256, 0, stream>>>(x, ff, ln2g, ln2b, (float*)d_out, 1);
}

// Round 3
// 708.981 us; speedup vs baseline: 2.7195x; 2.7195x over previous
//
#include <hip/hip_runtime.h>

typedef unsigned short u16;
typedef short bf16x8 __attribute__((ext_vector_type(8)));
typedef float f32x4 __attribute__((ext_vector_type(4)));

#define BB 2
#define TT 1024
#define DD 768
#define HH 12
#define HD 64
#define FFD 3072
#define NE 4
#define NTOK (BB*TT)

__device__ __forceinline__ float us2f(u16 u) {
    return __uint_as_float(((unsigned int)u) << 16);
}
__device__ __forceinline__ u16 f2us(float f) {
    unsigned int x = __float_as_uint(f);
    x += 0x7fffu + ((x >> 16) & 1u);
    return (u16)(x >> 16);
}

// ---------------------------------------------------------------------------
// Flat fp32 -> bf16 convert. n must be multiple of 8.
// ---------------------------------------------------------------------------
__global__ __launch_bounds__(256) void convert_kernel(
    const float* __restrict__ in, u16* __restrict__ out, int n8)
{
    int i = blockIdx.x * 256 + threadIdx.x;
    if (i >= n8) return;
    const float4* p = reinterpret_cast<const float4*>(in) + (size_t)i * 2;
    float4 a = p[0], b = p[1];
    u16 o[8] = {f2us(a.x), f2us(a.y), f2us(a.z), f2us(a.w),
                f2us(b.x), f2us(b.y), f2us(b.z), f2us(b.w)};
    *reinterpret_cast<uint4*>(out + (size_t)i * 8) = *reinterpret_cast<uint4*>(o);
}

// ---------------------------------------------------------------------------
// Transpose + convert: src [R,C] fp32 row-major -> dst bf16, dst[c*dstStride+r].
// Grid: (C/32, R/32), 256 threads.
// ---------------------------------------------------------------------------
__global__ __launch_bounds__(256) void transpose_convert_kernel(
    const float* __restrict__ src, u16* __restrict__ dst,
    int R, int C, int dstStride)
{
    __shared__ float tile[32][33];
    const int c0 = blockIdx.x * 32, r0 = blockIdx.y * 32;
    const int tx = threadIdx.x & 31, ty = threadIdx.x >> 5;
    #pragma unroll
    for (int it = 0; it < 4; it++) {
        int r = ty + it * 8;
        tile[r][tx] = src[(size_t)(r0 + r) * C + c0 + tx];
    }
    __syncthreads();
    #pragma unroll
    for (int it = 0; it < 4; it++) {
        int c = ty + it * 8;
        dst[(size_t)(c0 + c) * dstStride + r0 + tx] = f2us(tile[tx][c]);
    }
}

// ---------------------------------------------------------------------------
// bf16 MFMA GEMM: C[M,N] = A[M,K] * Bt[N,K]^T  (both row-major, K-contiguous)
// 128x128 tile, 4 waves, 16x16x32 MFMA, fp32 accum.
// modes:
//  0 QKV:  y=acc+biasF[n]; scatter fp32 to outF (Q|K|V [B,H,T,64] contiguous)
//  1 Wo:   y=acc+biasF[n]+src[m*N+n] -> outF fp32 [M,N]
//  2 FF1:  y=relu(acc+biasF[z*biasZ+n])*comb[m*4+z] -> bf16 outH[m*ldc+cZ*z+n]
//  3 FF2:  y=acc+comb[m*4+z]*biasF[z*biasZ+n] -> fp32 outF[z*cZ+m*ldc+n]
// ---------------------------------------------------------------------------
__global__ __launch_bounds__(256) void gemm_bt_kernel(
    const u16* __restrict__ A, int lda, long aZ,
    const u16* __restrict__ Bt, int ldb, long bZ,
    int K, int mode,
    float* __restrict__ outF, u16* __restrict__ outH, int ldc, long cZ,
    const float* __restrict__ biasF, int biasZ,
    const float* __restrict__ src, const float* __restrict__ comb)
{
    __shared__ u16 As[128][40];
    __shared__ u16 Bs[128][40];
    const int tid = threadIdx.x;
    const int z = blockIdx.z;
    const int m0 = blockIdx.y * 128, n0 = blockIdx.x * 128;
    const u16* Ab = A + (size_t)z * aZ;
    const u16* Bb = Bt + (size_t)z * bZ;

    const int wave = tid >> 6, lane = tid & 63;
    const int wm = (wave & 1) * 64, wn = (wave >> 1) * 64;
    const int fm = lane & 15;
    const int q8 = (lane >> 4) * 8;

    const int srow = tid >> 2;          // 0..63
    const int sseg = (tid & 3) * 8;     // 0,8,16,24

    f32x4 acc[4][4] = {};

    for (int k0 = 0; k0 < K; k0 += 32) {
        *reinterpret_cast<uint4*>(&As[srow][sseg]) =
            *reinterpret_cast<const uint4*>(Ab + (size_t)(m0 + srow) * lda + k0 + sseg);
        *reinterpret_cast<uint4*>(&As[srow + 64][sseg]) =
            *reinterpret_cast<const uint4*>(Ab + (size_t)(m0 + srow + 64) * lda + k0 + sseg);
        *reinterpret_cast<uint4*>(&Bs[srow][sseg]) =
            *reinterpret_cast<const uint4*>(Bb + (size_t)(n0 + srow) * ldb + k0 + sseg);
        *reinterpret_cast<uint4*>(&Bs[srow + 64][sseg]) =
            *reinterpret_cast<const uint4*>(Bb + (size_t)(n0 + srow + 64) * ldb + k0 + sseg);
        __syncthreads();

        bf16x8 af[4], bf[4];
        #pragma unroll
        for (int i = 0; i < 4; i++)
            af[i] = *reinterpret_cast<const bf16x8*>(&As[wm + i * 16 + fm][q8]);
        #pragma unroll
        for (int j = 0; j < 4; j++)
            bf[j] = *reinterpret_cast<const bf16x8*>(&Bs[wn + j * 16 + fm][q8]);
        #pragma unroll
        for (int i = 0; i < 4; i++)
            #pragma unroll
            for (int j = 0; j < 4; j++)
                acc[i][j] = __builtin_amdgcn_mfma_f32_16x16x32_bf16(
                    af[i], bf[j], acc[i][j], 0, 0, 0);
        __syncthreads();
    }

    // C/D layout: col = lane&15, row = (lane>>4)*4 + reg   [m89-verified]
    const int cn = lane & 15, cr = (lane >> 4) * 4;
    #pragma unroll
    for (int i = 0; i < 4; i++) {
        #pragma unroll
        for (int j = 0; j < 4; j++) {
            const int n = n0 + wn + j * 16 + cn;
            #pragma unroll
            for (int r = 0; r < 4; r++) {
                const int m = m0 + wm + i * 16 + cr + r;
                float y = acc[i][j][r];
                if (mode == 0) {
                    y += biasF[n];
                    int which = (n >= 1536) ? 2 : (n >= 768 ? 1 : 0);
                    int nn = n - which * 768;
                    int bb = m >> 10, t = m & 1023;
                    int h = nn >> 6, d = nn & 63;
                    outF[(size_t)which * (BB * HH * TT * HD)
                         + (((size_t)(bb * HH + h) * TT + t) << 6) + d] = y;
                } else if (mode == 1) {
                    size_t idx = (size_t)m * ldc + n;
                    outF[idx] = y + biasF[n] + src[idx];
                } else if (mode == 2) {
                    y = fmaxf(y + biasF[(size_t)z * biasZ + n], 0.f) * comb[m * NE + z];
                    outH[(size_t)m * ldc + (size_t)z * cZ + n] = f2us(y);
                } else {
                    y += comb[m * NE + z] * biasF[(size_t)z * biasZ + n];
                    outF[(size_t)z * cZ + (size_t)m * ldc + n] = y;
                }
            }
        }
    }
}

// ---------------------------------------------------------------------------
// Attention: per block = (b, h, 32 q-rows). Two passes over K (fp32 in, bf16 out).
// probs = softmax(a*l), a = gamma/(std_ddof1(l)+1e-5); shift cancels in softmax.
// ---------------------------------------------------------------------------
__global__ __launch_bounds__(256) void attn_kernel(
    const float* __restrict__ Qb, const float* __restrict__ Kb,
    const float* __restrict__ Vb, const float* __restrict__ gamma_p,
    u16* __restrict__ attn_out)
{
    const int qt = blockIdx.x, h = blockIdx.y, b = blockIdx.z;
    __shared__ float Qs[32][68];
    __shared__ float Ks[64][68];
    __shared__ float Vs[64][68];
    __shared__ float Ps[32][68];
    __shared__ float aArr[32], cmArr[32], dArr[32];
    const int tid = threadIdx.x;
    const float scale = 0.125f;
    const float gamma = gamma_p[0];
    const float* Qh = Qb + (size_t)(b * HH + h) * TT * HD;
    const float* Kh = Kb + (size_t)(b * HH + h) * TT * HD;
    const float* Vh = Vb + (size_t)(b * HH + h) * TT * HD;
    const int m0 = qt * 32;

    for (int i = tid; i < 32 * 64; i += 256) {
        int r = i >> 6, c = i & 63;
        Qs[r][c] = Qh[(size_t)(m0 + r) * HD + c] * scale;
    }
    __syncthreads();

    const int q = tid >> 3, l = tid & 7;
    float s1 = 0.f, s2 = 0.f, mx = -1e30f, mn = 1e30f;
    for (int kt = 0; kt < TT; kt += 64) {
        for (int i = tid; i < 64 * 64; i += 256) {
            int r = i >> 6, c = i & 63;
            Ks[r][c] = Kh[(size_t)(kt + r) * HD + c];
        }
        __syncthreads();
        for (int kk = l; kk < 64; kk += 8) {
            float lv = 0.f;
            #pragma unroll
            for (int d4 = 0; d4 < 16; d4++) {
                float4 qa = *reinterpret_cast<const float4*>(&Qs[q][d4 * 4]);
                float4 ka = *reinterpret_cast<const float4*>(&Ks[kk][d4 * 4]);
                lv = fmaf(qa.x, ka.x, lv); lv = fmaf(qa.y, ka.y, lv);
                lv = fmaf(qa.z, ka.z, lv); lv = fmaf(qa.w, ka.w, lv);
            }
            s1 += lv; s2 += lv * lv;
            mx = fmaxf(mx, lv); mn = fminf(mn, lv);
        }
        __syncthreads();
    }
    #pragma unroll
    for (int off = 4; off > 0; off >>= 1) {
        s1 += __shfl_down(s1, off, 8);
        s2 += __shfl_down(s2, off, 8);
        mx = fmaxf(mx, __shfl_down(mx, off, 8));
        mn = fminf(mn, __shfl_down(mn, off, 8));
    }
    if (l == 0) {
        float var = (s2 - s1 * s1 / (float)TT) / (float)(TT - 1);
        var = fmaxf(var, 0.f);
        float a = gamma / (sqrtf(var) + 1e-5f);
        aArr[q] = a;
        cmArr[q] = (a >= 0.f) ? a * mx : a * mn;
    }
    __syncthreads();
    const float a = aArr[q], cm = cmArr[q];
    float dpart = 0.f;
    float Oacc[8] = {};
    for (int kt = 0; kt < TT; kt += 64) {
        for (int i = tid; i < 64 * 64; i += 256) {
            int r = i >> 6, c = i & 63;
            Ks[r][c] = Kh[(size_t)(kt + r) * HD + c];
            Vs[r][c] = Vh[(size_t)(kt + r) * HD + c];
        }
        __syncthreads();
        for (int kk = l; kk < 64; kk += 8) {
            float lv = 0.f;
            #pragma unroll
            for (int d4 = 0; d4 < 16; d4++) {
                float4 qa = *reinterpret_cast<const float4*>(&Qs[q][d4 * 4]);
                float4 ka = *reinterpret_cast<const float4*>(&Ks[kk][d4 * 4]);
                lv = fmaf(qa.x, ka.x, lv); lv = fmaf(qa.y, ka.y, lv);
                lv = fmaf(qa.z, ka.z, lv); lv = fmaf(qa.w, ka.w, lv);
            }
            float p = __expf(a * lv - cm);
            Ps[q][kk] = p;
            dpart += p;
        }
        __syncthreads();
        for (int kk = 0; kk < 64; kk++) {
            float p = Ps[q][kk];
            #pragma unroll
            for (int j = 0; j < 8; j++) Oacc[j] += p * Vs[kk][l * 8 + j];
        }
        __syncthreads();
    }
    #pragma unroll
    for (int off = 4; off > 0; off >>= 1) dpart += __shfl_down(dpart, off, 8);
    if (l == 0) dArr[q] = dpart;
    __syncthreads();
    const float dinv = 1.f / dArr[q];
    const int t = m0 + q;
    u16* orow = attn_out + ((size_t)(b * TT + t)) * DD + h * HD + l * 8;
    #pragma unroll
    for (int j = 0; j < 8; j++) orow[j] = f2us(Oacc[j] * dinv);
}

// ---------------------------------------------------------------------------
// LayerNorm over D=768.
// mode 0: in1 -> outF fp32 + outH bf16.
// mode 1: in1 + p0+p1+p2+p3 -> outF fp32.
// ---------------------------------------------------------------------------
__global__ __launch_bounds__(256) void ln_kernel(
    const float* __restrict__ in1,
    const float* __restrict__ p0, const float* __restrict__ p1,
    const float* __restrict__ p2, const float* __restrict__ p3,
    const float* __restrict__ g, const float* __restrict__ bta,
    float* __restrict__ outF, u16* __restrict__ outH, int mode)
{
    const int row = blockIdx.x, tid = threadIdx.x;
    __shared__ float red[256];
    const size_t base = (size_t)row * DD;
    float v[3];
    #pragma unroll
    for (int i = 0; i < 3; i++) {
        int c = tid + i * 256;
        float t = in1[base + c];
        if (mode == 1) t += p0[base + c] + p1[base + c] + p2[base + c] + p3[base + c];
        v[i] = t;
    }
    float s = v[0] + v[1] + v[2];
    red[tid] = s; __syncthreads();
    #pragma unroll
    for (int o = 128; o > 0; o >>= 1) { if (tid < o) red[tid] += red[tid + o]; __syncthreads(); }
    const float mean = red[0] * (1.f / 768.f);
    __syncthreads();
    float qv = 0.f;
    #pragma unroll
    for (int i = 0; i < 3; i++) { float d = v[i] - mean; qv += d * d; }
    red[tid] = qv; __syncthreads();
    #pragma unroll
    for (int o = 128; o > 0; o >>= 1) { if (tid < o) red[tid] += red[tid + o]; __syncthreads(); }
    const float var = red[0] * (1.f / 768.f);
    const float rs = rsqrtf(var + 1e-5f);
    #pragma unroll
    for (int i = 0; i < 3; i++) {
        int c = tid + i * 256;
        float o = (v[i] - mean) * rs * g[c] + bta[c];
        outF[base + c] = o;
        if (mode == 0) outH[base + c] = f2us(o);
    }
}

// ---------------------------------------------------------------------------
// Gate: one wave per token. softmax over E=4, top-2 -> combine weights.
// ---------------------------------------------------------------------------
__global__ __launch_bounds__(256) void gate_kernel(
    const float* __restrict__ x, const float* __restrict__ Wg,
    const float* __restrict__ bg, float* __restrict__ comb)
{
    const int wid = threadIdx.x >> 6, lane = threadIdx.x & 63;
    const int t = blockIdx.x * 4 + wid;
    const float* xr = x + (size_t)t * DD;
    float g[NE];
    #pragma unroll
    for (int e = 0; e < NE; e++) {
        float p = 0.f;
        for (int d = lane; d < DD; d += 64) p += xr[d] * Wg[e * DD + d];
        #pragma unroll
        for (int off = 32; off > 0; off >>= 1) p += __shfl_down(p, off, 64);
        g[e] = p;
    }
    if (lane == 0) {
        float m = -1e30f;
        #pragma unroll
        for (int e = 0; e < NE; e++) { g[e] += bg[e]; m = fmaxf(m, g[e]); }
        float ex[NE], s = 0.f;
        #pragma unroll
        for (int e = 0; e < NE; e++) { ex[e] = __expf(g[e] - m); s += ex[e]; }
        #pragma unroll
        for (int e = 0; e < NE; e++) ex[e] /= s;
        int e1 = 0;
        #pragma unroll
        for (int e = 1; e < NE; e++) if (ex[e] > ex[e1]) e1 = e;
        int e2 = -1;
        #pragma unroll
        for (int e = 0; e < NE; e++) if (e != e1 && (e2 < 0 || ex[e] > ex[e2])) e2 = e;
        float c[NE] = {0.f, 0.f, 0.f, 0.f};
        c[e1] = ex[e1]; c[e2] = ex[e2];
        #pragma unroll
        for (int e = 0; e < NE; e++) comb[(size_t)t * NE + e] = c[e];
    }
}

extern "C" void kernel_launch(void* const* d_in, const int* in_sizes, int n_in,
                              void* d_out, int out_size, void* d_ws, size_t ws_size,
                              hipStream_t stream)
{
    const float* src  = (const float*)d_in[0];
    const float* Wq   = (const float*)d_in[2];  const float* bq = (const float*)d_in[3];
    const float* Wk   = (const float*)d_in[4];  const float* bk = (const float*)d_in[5];
    const float* Wv   = (const float*)d_in[6];  const float* bv = (const float*)d_in[7];
    const float* Wo   = (const float*)d_in[8];  const float* bo = (const float*)d_in[9];
    const float* gam  = (const float*)d_in[10];
    const float* ln1g = (const float*)d_in[11]; const float* ln1b = (const float*)d_in[12];
    const float* ln2g = (const float*)d_in[13]; const float* ln2b = (const float*)d_in[14];
    const float* Wg   = (const float*)d_in[15]; const float* bg = (const float*)d_in[16];
    const float* W1   = (const float*)d_in[17]; const float* b1 = (const float*)d_in[18];
    const float* W2   = (const float*)d_in[19]; const float* b2 = (const float*)d_in[20];
    (void)ws_size; (void)in_sizes; (void)n_in; (void)out_size;

    char* ws = (char*)d_ws;
    // persistent regions
    u16*   W1T  = (u16*)(ws);                              // 18,874,368 B
    u16*   W2T  = (u16*)(ws + 18874368);                   // 18,874,368 B
    u16*   hb   = (u16*)(ws + 37748736);                   // 50,331,648 B
    float* x    = (float*)(ws + 88080384);                 //  6,291,456 B
    u16*   xh   = (u16*)(ws + 94371840);                   //  3,145,728 B
    float* ffp  = (float*)(ws + 97517568);                 // 25,165,824 B (4 partials)
    float* comb = (float*)(ws + 122683392);                //     32,768 B
    float* bqkv = (float*)(ws + 122716160);                //      9,216 B
    // aliases inside hb region (dead before FF1 writes hb)
    char* H = ws + 37748736;
    float* QKVb   = (float*)(H);                           // 18,874,368 B (Q|K|V)
    u16*   src_h  = (u16*)(H + 18874368);                  //  3,145,728 B
    u16*   attn_h = (u16*)(H + 22020096);                  //  3,145,728 B
    u16*   WqkvH  = (u16*)(H + 25165824);                  //  3,538,944 B
    u16*   WoH    = (u16*)(H + 28704768);                  //  1,179,648 B
    float* r1     = (float*)(H + 29884416);                //  6,291,456 B

    const int DW = DD * DD;  // 589824

    // ---- weight/activation conversions ----
    convert_kernel<<<(NTOK * DD / 8 + 255) / 256, 256, 0, stream>>>(src, src_h, NTOK * DD / 8);
    convert_kernel<<<(DW / 8 + 255) / 256, 256, 0, stream>>>(Wq, WqkvH, DW / 8);
    convert_kernel<<<(DW / 8 + 255) / 256, 256, 0, stream>>>(Wk, WqkvH + DW, DW / 8);
    convert_kernel<<<(DW / 8 + 255) / 256, 256, 0, stream>>>(Wv, WqkvH + 2 * DW, DW / 8);
    convert_kernel<<<(DW / 8 + 255) / 256, 256, 0, stream>>>(Wo, WoH, DW / 8);
    hipMemcpyAsync(bqkv, bq, DD * 4, hipMemcpyDeviceToDevice, stream);
    hipMemcpyAsync(bqkv + DD, bk, DD * 4, hipMemcpyDeviceToDevice, stream);
    hipMemcpyAsync(bqkv + 2 * DD, bv, DD * 4, hipMemcpyDeviceToDevice, stream);
    for (int e = 0; e < NE; e++) {
        // W1[e]: [768,3072] -> W1T+e*FFD*DD as [3072,768]
        transpose_convert_kernel<<<dim3(FFD / 32, DD / 32), 256, 0, stream>>>(
            W1 + (size_t)e * DD * FFD, W1T + (size_t)e * FFD * DD, DD, FFD, DD);
        // W2[e]: [3072,768] -> W2T_all[n][e*3072+k], row stride 12288
        transpose_convert_kernel<<<dim3(DD / 32, FFD / 32), 256, 0, stream>>>(
            W2 + (size_t)e * FFD * DD, W2T + (size_t)e * FFD, FFD, DD, NE * FFD);
    }

    // ---- QKV (batched, N=2304) ----
    gemm_bt_kernel<<<dim3(2304 / 128, NTOK / 128, 1), 256, 0, stream>>>(
        src_h, DD, 0, WqkvH, DD, 0, DD, 0,
        QKVb, nullptr, 0, 0, bqkv, 0, nullptr, nullptr);

    // ---- attention ----
    float* Qb = QKVb;
    float* Kb = QKVb + (size_t)BB * HH * TT * HD;
    float* Vb = QKVb + 2 * (size_t)BB * HH * TT * HD;
    attn_kernel<<<dim3(TT / 32, HH, BB), 256, 0, stream>>>(Qb, Kb, Vb, gam, attn_h);

    // ---- Wo projection + residual ----
    gemm_bt_kernel<<<dim3(DD / 128, NTOK / 128, 1), 256, 0, stream>>>(
        attn_h, DD, 0, WoH, DD, 0, DD, 1,
        r1, nullptr, DD, 0, bo, 0, src, nullptr);

    // ---- LN1 ----
    ln_kernel<<<NTOK, 256, 0, stream>>>(r1, nullptr, nullptr, nullptr, nullptr,
                                        ln1g, ln1b, x, xh, 0);

    // ---- gate ----
    gate_kernel<<<NTOK / 4, 256, 0, stream>>>(x, Wg, bg, comb);

    // ---- FF1 (all experts, comb folded in) ----
    gemm_bt_kernel<<<dim3(FFD / 128, NTOK / 128, NE), 256, 0, stream>>>(
        xh, DD, 0, W1T, DD, (long)FFD * DD, DD, 2,
        nullptr, hb, NE * FFD, FFD, b1, FFD, nullptr, comb);

    // ---- FF2 (split over experts -> 4 partial buffers) ----
    gemm_bt_kernel<<<dim3(DD / 128, NTOK / 128, NE), 256, 0, stream>>>(
        hb, NE * FFD, FFD, W2T, NE * FFD, FFD, FFD, 3,
        ffp, nullptr, DD, (long)NTOK * DD, b2, DD, nullptr, comb);

    // ---- LN2 (sums partials inline) ----
    ln_kernel<<<NTOK, 256, 0, stream>>>(
        x, ffp, ffp + (size_t)NTOK * DD, ffp + 2 * (size_t)NTOK * DD,
        ffp + 3 * (size_t)NTOK * DD,
        ln2g, ln2b, (float*)d_out, nullptr, 1);
}

// Round 4
// 540.070 us; speedup vs baseline: 3.5701x; 1.3128x over previous
//
#include <hip/hip_runtime.h>

typedef unsigned short u16;
typedef short bf16x8 __attribute__((ext_vector_type(8)));
typedef float f32x4 __attribute__((ext_vector_type(4)));

#define BB 2
#define TT 1024
#define DD 768
#define HH 12
#define HD 64
#define FFD 3072
#define NE 4
#define NTOK (BB*TT)

#define MFMA16(a, b, c) __builtin_amdgcn_mfma_f32_16x16x32_bf16((a), (b), (c), 0, 0, 0)

__device__ __forceinline__ float us2f(u16 u) {
    return __uint_as_float(((unsigned int)u) << 16);
}
__device__ __forceinline__ u16 f2us(float f) {
    unsigned int x = __float_as_uint(f);
    x += 0x7fffu + ((x >> 16) & 1u);
    return (u16)(x >> 16);
}

// ---------------------------------------------------------------------------
// Flat fp32 -> bf16 convert. n8 = n/8 work items.
// ---------------------------------------------------------------------------
__global__ __launch_bounds__(256) void convert_kernel(
    const float* __restrict__ in, u16* __restrict__ out, int n8)
{
    int i = blockIdx.x * 256 + threadIdx.x;
    if (i >= n8) return;
    const float4* p = reinterpret_cast<const float4*>(in) + (size_t)i * 2;
    float4 a = p[0], b = p[1];
    u16 o[8] = {f2us(a.x), f2us(a.y), f2us(a.z), f2us(a.w),
                f2us(b.x), f2us(b.y), f2us(b.z), f2us(b.w)};
    *reinterpret_cast<uint4*>(out + (size_t)i * 8) = *reinterpret_cast<uint4*>(o);
}

// ---------------------------------------------------------------------------
// Transpose + convert: src [R,C] fp32 row-major -> dst bf16, dst[c*dstStride+r].
// ---------------------------------------------------------------------------
__global__ __launch_bounds__(256) void transpose_convert_kernel(
    const float* __restrict__ src, u16* __restrict__ dst,
    int R, int C, int dstStride)
{
    __shared__ float tile[32][33];
    const int c0 = blockIdx.x * 32, r0 = blockIdx.y * 32;
    const int tx = threadIdx.x & 31, ty = threadIdx.x >> 5;
    #pragma unroll
    for (int it = 0; it < 4; it++) {
        int r = ty + it * 8;
        tile[r][tx] = src[(size_t)(r0 + r) * C + c0 + tx];
    }
    __syncthreads();
    #pragma unroll
    for (int it = 0; it < 4; it++) {
        int c = ty + it * 8;
        dst[(size_t)(c0 + c) * dstStride + r0 + tx] = f2us(tile[tx][c]);
    }
}

// ---------------------------------------------------------------------------
// bf16 MFMA GEMM: C[M,N] = A[M,K] * Bt[N,K]^T  (both row-major, K-contiguous)
// 128x128 tile, 4 waves, 16x16x32 MFMA, fp32 accum.
// modes:
//  0 QKV:  y=acc+biasF[n]; bf16 scatter: Q,K -> [B,H,T,64]; V -> VT [B,H,64,T]
//  1 Wo:   y=acc+biasF[n]+src[m*N+n] -> outF fp32 [M,N]
//  2 FF1:  y=relu(acc+biasF[z*biasZ+n])*comb[m*4+z] -> bf16 outH[m*ldc+cZ*z+n]
//  3 FF2:  y=acc+comb[m*4+z]*biasF[z*biasZ+n] -> fp32 outF[z*cZ+m*ldc+n]
// ---------------------------------------------------------------------------
__global__ __launch_bounds__(256) void gemm_bt_kernel(
    const u16* __restrict__ A, int lda, long aZ,
    const u16* __restrict__ Bt, int ldb, long bZ,
    int K, int mode,
    float* __restrict__ outF, u16* __restrict__ outH,
    u16* __restrict__ outH2, u16* __restrict__ outH3,
    int ldc, long cZ,
    const float* __restrict__ biasF, int biasZ,
    const float* __restrict__ src, const float* __restrict__ comb)
{
    __shared__ u16 As[128][40];
    __shared__ u16 Bs[128][40];
    const int tid = threadIdx.x;
    const int z = blockIdx.z;
    const int m0 = blockIdx.y * 128, n0 = blockIdx.x * 128;
    const u16* Ab = A + (size_t)z * aZ;
    const u16* Bb = Bt + (size_t)z * bZ;

    const int wave = tid >> 6, lane = tid & 63;
    const int wm = (wave & 1) * 64, wn = (wave >> 1) * 64;
    const int fm = lane & 15;
    const int q8 = (lane >> 4) * 8;

    const int srow = tid >> 2;
    const int sseg = (tid & 3) * 8;

    f32x4 acc[4][4] = {};

    for (int k0 = 0; k0 < K; k0 += 32) {
        *reinterpret_cast<uint4*>(&As[srow][sseg]) =
            *reinterpret_cast<const uint4*>(Ab + (size_t)(m0 + srow) * lda + k0 + sseg);
        *reinterpret_cast<uint4*>(&As[srow + 64][sseg]) =
            *reinterpret_cast<const uint4*>(Ab + (size_t)(m0 + srow + 64) * lda + k0 + sseg);
        *reinterpret_cast<uint4*>(&Bs[srow][sseg]) =
            *reinterpret_cast<const uint4*>(Bb + (size_t)(n0 + srow) * ldb + k0 + sseg);
        *reinterpret_cast<uint4*>(&Bs[srow + 64][sseg]) =
            *reinterpret_cast<const uint4*>(Bb + (size_t)(n0 + srow + 64) * ldb + k0 + sseg);
        __syncthreads();

        bf16x8 af[4], bf[4];
        #pragma unroll
        for (int i = 0; i < 4; i++)
            af[i] = *reinterpret_cast<const bf16x8*>(&As[wm + i * 16 + fm][q8]);
        #pragma unroll
        for (int j = 0; j < 4; j++)
            bf[j] = *reinterpret_cast<const bf16x8*>(&Bs[wn + j * 16 + fm][q8]);
        #pragma unroll
        for (int i = 0; i < 4; i++)
            #pragma unroll
            for (int j = 0; j < 4; j++)
                acc[i][j] = MFMA16(af[i], bf[j], acc[i][j]);
        __syncthreads();
    }

    // C/D layout: col = lane&15, row = (lane>>4)*4 + reg   [m89-verified]
    const int cn = lane & 15, cr = (lane >> 4) * 4;
    #pragma unroll
    for (int i = 0; i < 4; i++) {
        #pragma unroll
        for (int j = 0; j < 4; j++) {
            const int n = n0 + wn + j * 16 + cn;
            #pragma unroll
            for (int r = 0; r < 4; r++) {
                const int m = m0 + wm + i * 16 + cr + r;
                float y = acc[i][j][r];
                if (mode == 0) {
                    y += biasF[n];
                    int which = (n >= 1536) ? 2 : (n >= 768 ? 1 : 0);
                    int nn = n - which * 768;
                    int bb = m >> 10, t = m & 1023;
                    int hh = nn >> 6, d = nn & 63;
                    if (which == 0)
                        outH[(((size_t)(bb * HH + hh) * TT + t) << 6) + d] = f2us(y);
                    else if (which == 1)
                        outH2[(((size_t)(bb * HH + hh) * TT + t) << 6) + d] = f2us(y);
                    else
                        outH3[(((size_t)(bb * HH + hh) * HD + d) << 10) + t] = f2us(y);
                } else if (mode == 1) {
                    size_t idx = (size_t)m * ldc + n;
                    outF[idx] = y + biasF[n] + src[idx];
                } else if (mode == 2) {
                    y = fmaxf(y + biasF[(size_t)z * biasZ + n], 0.f) * comb[m * NE + z];
                    outH[(size_t)m * ldc + (size_t)z * cZ + n] = f2us(y);
                } else {
                    y += comb[m * NE + z] * biasF[(size_t)z * biasZ + n];
                    outF[(size_t)z * cZ + (size_t)m * ldc + n] = y;
                }
            }
        }
    }
}

// ---------------------------------------------------------------------------
// MFMA attention. Block = (qt 32 rows, b*12+h). 4 waves.
// Phase 1: S[32][1024] in accumulators (wave w covers cols w*256..+256).
// zscore is scale-invariant: a = gamma/(std_ddof1(S)+EPS_Z/0.125); shift
// cancels in softmax; cm = max(a*S) for stability.
// Phase 2: P bf16 in LDS; O = P*V via MFMA (V pre-transposed [B,H,64,T]).
// ---------------------------------------------------------------------------
#define PSTR 1032  // u16 stride: byte stride 2064 (16B aligned), dw 516 ≡ 4 mod 8 -> conflict-free b128
__global__ __launch_bounds__(256, 2) void attn_mfma_kernel(
    const u16* __restrict__ Qh, const u16* __restrict__ Kh,
    const u16* __restrict__ VT, const float* __restrict__ gamma_p,
    u16* __restrict__ attn_out)
{
    __shared__ __align__(16) u16 P[32 * PSTR];
    __shared__ float wred[4][32][4];
    __shared__ float dred[4][32];
    __shared__ float aArr[32], cmArr[32], dinvArr[32];

    const int qt = blockIdx.x, bh = blockIdx.y;
    const int b = bh / HH, h = bh - b * HH;
    const int tid = threadIdx.x, wave = tid >> 6, lane = tid & 63;
    const int g = lane >> 4, fm = lane & 15;
    const float gamma = gamma_p[0];
    const int m0 = qt * 32;
    const u16* Qp = Qh + (size_t)bh * TT * HD;
    const u16* Kp = Kh + (size_t)bh * TT * HD;
    const u16* Vp = VT + (size_t)bh * HD * TT;

    // Q A-frags (2 m-tiles x 2 k-steps)
    bf16x8 af[2][2];
    #pragma unroll
    for (int mi = 0; mi < 2; mi++)
        #pragma unroll
        for (int ks = 0; ks < 2; ks++)
            af[mi][ks] = *reinterpret_cast<const bf16x8*>(
                Qp + (size_t)(m0 + mi * 16 + fm) * HD + ks * 32 + g * 8);

    const int n0w = wave * 256;
    f32x4 acc[16][2] = {};
    #pragma unroll
    for (int nj = 0; nj < 16; nj++) {
        const u16* kp = Kp + (size_t)(n0w + nj * 16 + fm) * HD + g * 8;
        bf16x8 b0 = *reinterpret_cast<const bf16x8*>(kp);
        bf16x8 b1 = *reinterpret_cast<const bf16x8*>(kp + 32);
        acc[nj][0] = MFMA16(af[0][0], b0, acc[nj][0]);
        acc[nj][0] = MFMA16(af[0][1], b1, acc[nj][0]);
        acc[nj][1] = MFMA16(af[1][0], b0, acc[nj][1]);
        acc[nj][1] = MFMA16(af[1][1], b1, acc[nj][1]);
    }

    // per-row stats from fp32 accumulators
    #pragma unroll
    for (int mi = 0; mi < 2; mi++) {
        #pragma unroll
        for (int r = 0; r < 4; r++) {
            float s1 = 0.f, s2 = 0.f, mx = -3.4e38f, mn = 3.4e38f;
            #pragma unroll
            for (int nj = 0; nj < 16; nj++) {
                float v = acc[nj][mi][r];
                s1 += v; s2 = fmaf(v, v, s2);
                mx = fmaxf(mx, v); mn = fminf(mn, v);
            }
            #pragma unroll
            for (int msk = 1; msk < 16; msk <<= 1) {
                s1 += __shfl_xor(s1, msk);
                s2 += __shfl_xor(s2, msk);
                mx = fmaxf(mx, __shfl_xor(mx, msk));
                mn = fminf(mn, __shfl_xor(mn, msk));
            }
            if (fm == 0) {
                int row = mi * 16 + g * 4 + r;
                wred[wave][row][0] = s1; wred[wave][row][1] = s2;
                wred[wave][row][2] = mx; wred[wave][row][3] = mn;
            }
        }
    }
    __syncthreads();
    if (tid < 32) {
        float s1 = 0.f, s2 = 0.f, mx = -3.4e38f, mn = 3.4e38f;
        #pragma unroll
        for (int w = 0; w < 4; w++) {
            s1 += wred[w][tid][0]; s2 += wred[w][tid][1];
            mx = fmaxf(mx, wred[w][tid][2]); mn = fminf(mn, wred[w][tid][3]);
        }
        float var = (s2 - s1 * s1 * (1.f / TT)) * (1.f / (TT - 1));
        var = fmaxf(var, 0.f);
        float a = gamma / (sqrtf(var) + 8e-5f);   // EPS_Z / scale, scale=0.125
        aArr[tid] = a;
        cmArr[tid] = (a >= 0.f) ? a * mx : a * mn;
    }
    __syncthreads();

    // softmax numerator -> P (bf16), accumulate denominator from rounded values
    #pragma unroll
    for (int mi = 0; mi < 2; mi++) {
        #pragma unroll
        for (int r = 0; r < 4; r++) {
            const int row = mi * 16 + g * 4 + r;
            const float a = aArr[row], cm = cmArr[row];
            float dp = 0.f;
            #pragma unroll
            for (int nj = 0; nj < 16; nj++) {
                float p = __expf(fmaf(a, acc[nj][mi][r], -cm));
                u16 pb = f2us(p);
                dp += us2f(pb);
                P[row * PSTR + n0w + nj * 16 + fm] = pb;
            }
            #pragma unroll
            for (int msk = 1; msk < 16; msk <<= 1) dp += __shfl_xor(dp, msk);
            if (fm == 0) dred[wave][row] = dp;
        }
    }
    __syncthreads();
    if (tid < 32)
        dinvArr[tid] = 1.f / (dred[0][tid] + dred[1][tid] + dred[2][tid] + dred[3][tid]);
    __syncthreads();

    // PV: O[32][64], wave covers 16 output dims
    f32x4 oacc[2] = {};
    #pragma unroll 4
    for (int ks = 0; ks < 32; ks++) {
        bf16x8 bv = *reinterpret_cast<const bf16x8*>(
            Vp + (size_t)(wave * 16 + fm) * TT + ks * 32 + g * 8);
        bf16x8 a0 = *reinterpret_cast<const bf16x8*>(&P[(size_t)fm * PSTR + ks * 32 + g * 8]);
        bf16x8 a1 = *reinterpret_cast<const bf16x8*>(&P[(size_t)(16 + fm) * PSTR + ks * 32 + g * 8]);
        oacc[0] = MFMA16(a0, bv, oacc[0]);
        oacc[1] = MFMA16(a1, bv, oacc[1]);
    }
    #pragma unroll
    for (int mi = 0; mi < 2; mi++) {
        #pragma unroll
        for (int r = 0; r < 4; r++) {
            int row = mi * 16 + g * 4 + r;
            int t = m0 + row;
            attn_out[((size_t)(b * TT + t)) * DD + h * HD + wave * 16 + fm] =
                f2us(oacc[mi][r] * dinvArr[row]);
        }
    }
}

// ---------------------------------------------------------------------------
// LayerNorm over D=768.
// mode 0: in1 -> outF fp32 + outH bf16.   mode 1: in1+p0+p1+p2+p3 -> outF.
// ---------------------------------------------------------------------------
__global__ __launch_bounds__(256) void ln_kernel(
    const float* __restrict__ in1,
    const float* __restrict__ p0, const float* __restrict__ p1,
    const float* __restrict__ p2, const float* __restrict__ p3,
    const float* __restrict__ g, const float* __restrict__ bta,
    float* __restrict__ outF, u16* __restrict__ outH, int mode)
{
    const int row = blockIdx.x, tid = threadIdx.x;
    __shared__ float red[256];
    const size_t base = (size_t)row * DD;
    float v[3];
    #pragma unroll
    for (int i = 0; i < 3; i++) {
        int c = tid + i * 256;
        float t = in1[base + c];
        if (mode == 1) t += p0[base + c] + p1[base + c] + p2[base + c] + p3[base + c];
        v[i] = t;
    }
    float s = v[0] + v[1] + v[2];
    red[tid] = s; __syncthreads();
    #pragma unroll
    for (int o = 128; o > 0; o >>= 1) { if (tid < o) red[tid] += red[tid + o]; __syncthreads(); }
    const float mean = red[0] * (1.f / 768.f);
    __syncthreads();
    float qv = 0.f;
    #pragma unroll
    for (int i = 0; i < 3; i++) { float d = v[i] - mean; qv += d * d; }
    red[tid] = qv; __syncthreads();
    #pragma unroll
    for (int o = 128; o > 0; o >>= 1) { if (tid < o) red[tid] += red[tid + o]; __syncthreads(); }
    const float var = red[0] * (1.f / 768.f);
    const float rs = rsqrtf(var + 1e-5f);
    #pragma unroll
    for (int i = 0; i < 3; i++) {
        int c = tid + i * 256;
        float o = (v[i] - mean) * rs * g[c] + bta[c];
        outF[base + c] = o;
        if (mode == 0) outH[base + c] = f2us(o);
    }
}

// ---------------------------------------------------------------------------
// Gate: one wave per token. softmax over E=4, top-2 -> combine weights.
// ---------------------------------------------------------------------------
__global__ __launch_bounds__(256) void gate_kernel(
    const float* __restrict__ x, const float* __restrict__ Wg,
    const float* __restrict__ bg, float* __restrict__ comb)
{
    const int wid = threadIdx.x >> 6, lane = threadIdx.x & 63;
    const int t = blockIdx.x * 4 + wid;
    const float* xr = x + (size_t)t * DD;
    float g[NE];
    #pragma unroll
    for (int e = 0; e < NE; e++) {
        float p = 0.f;
        for (int d = lane; d < DD; d += 64) p += xr[d] * Wg[e * DD + d];
        #pragma unroll
        for (int off = 32; off > 0; off >>= 1) p += __shfl_down(p, off, 64);
        g[e] = p;
    }
    if (lane == 0) {
        float m = -1e30f;
        #pragma unroll
        for (int e = 0; e < NE; e++) { g[e] += bg[e]; m = fmaxf(m, g[e]); }
        float ex[NE], s = 0.f;
        #pragma unroll
        for (int e = 0; e < NE; e++) { ex[e] = __expf(g[e] - m); s += ex[e]; }
        #pragma unroll
        for (int e = 0; e < NE; e++) ex[e] /= s;
        int e1 = 0;
        #pragma unroll
        for (int e = 1; e < NE; e++) if (ex[e] > ex[e1]) e1 = e;
        int e2 = -1;
        #pragma unroll
        for (int e = 0; e < NE; e++) if (e != e1 && (e2 < 0 || ex[e] > ex[e2])) e2 = e;
        float c[NE] = {0.f, 0.f, 0.f, 0.f};
        c[e1] = ex[e1]; c[e2] = ex[e2];
        #pragma unroll
        for (int e = 0; e < NE; e++) comb[(size_t)t * NE + e] = c[e];
    }
}

extern "C" void kernel_launch(void* const* d_in, const int* in_sizes, int n_in,
                              void* d_out, int out_size, void* d_ws, size_t ws_size,
                              hipStream_t stream)
{
    const float* src  = (const float*)d_in[0];
    const float* Wq   = (const float*)d_in[2];  const float* bq = (const float*)d_in[3];
    const float* Wk   = (const float*)d_in[4];  const float* bk = (const float*)d_in[5];
    const float* Wv   = (const float*)d_in[6];  const float* bv = (const float*)d_in[7];
    const float* Wo   = (const float*)d_in[8];  const float* bo = (const float*)d_in[9];
    const float* gam  = (const float*)d_in[10];
    const float* ln1g = (const float*)d_in[11]; const float* ln1b = (const float*)d_in[12];
    const float* ln2g = (const float*)d_in[13]; const float* ln2b = (const float*)d_in[14];
    const float* Wg   = (const float*)d_in[15]; const float* bg = (const float*)d_in[16];
    const float* W1   = (const float*)d_in[17]; const float* b1 = (const float*)d_in[18];
    const float* W2   = (const float*)d_in[19]; const float* b2 = (const float*)d_in[20];
    (void)ws_size; (void)in_sizes; (void)n_in; (void)out_size;

    char* ws = (char*)d_ws;
    // persistent regions
    u16*   W1T  = (u16*)(ws);                              // 18,874,368 B
    u16*   W2T  = (u16*)(ws + 18874368);                   // 18,874,368 B
    u16*   hb   = (u16*)(ws + 37748736);                   // 50,331,648 B
    float* x    = (float*)(ws + 88080384);                 //  6,291,456 B
    u16*   xh   = (u16*)(ws + 94371840);                   //  3,145,728 B
    float* ffp  = (float*)(ws + 97517568);                 // 25,165,824 B (4 partials)
    float* comb = (float*)(ws + 122683392);                //     32,768 B
    float* bqkv = (float*)(ws + 122716160);                //      9,216 B
    // aliases inside hb region (all dead before FF1 writes hb)
    char* H = ws + 37748736;
    u16*   Qh     = (u16*)(H);                             //  3,145,728 B
    u16*   Kh     = (u16*)(H + 3145728);                   //  3,145,728 B
    u16*   VTh    = (u16*)(H + 6291456);                   //  3,145,728 B
    u16*   src_h  = (u16*)(H + 9437184);                   //  3,145,728 B
    u16*   attn_h = (u16*)(H + 12582912);                  //  3,145,728 B
    u16*   WqkvH  = (u16*)(H + 15728640);                  //  3,538,944 B
    u16*   WoH    = (u16*)(H + 19267584);                  //  1,179,648 B
    float* r1     = (float*)(H + 20447232);                //  6,291,456 B

    const int DW = DD * DD;  // 589824

    // ---- weight/activation conversions ----
    convert_kernel<<<(NTOK * DD / 8 + 255) / 256, 256, 0, stream>>>(src, src_h, NTOK * DD / 8);
    convert_kernel<<<(DW / 8 + 255) / 256, 256, 0, stream>>>(Wq, WqkvH, DW / 8);
    convert_kernel<<<(DW / 8 + 255) / 256, 256, 0, stream>>>(Wk, WqkvH + DW, DW / 8);
    convert_kernel<<<(DW / 8 + 255) / 256, 256, 0, stream>>>(Wv, WqkvH + 2 * DW, DW / 8);
    convert_kernel<<<(DW / 8 + 255) / 256, 256, 0, stream>>>(Wo, WoH, DW / 8);
    hipMemcpyAsync(bqkv, bq, DD * 4, hipMemcpyDeviceToDevice, stream);
    hipMemcpyAsync(bqkv + DD, bk, DD * 4, hipMemcpyDeviceToDevice, stream);
    hipMemcpyAsync(bqkv + 2 * DD, bv, DD * 4, hipMemcpyDeviceToDevice, stream);
    for (int e = 0; e < NE; e++) {
        transpose_convert_kernel<<<dim3(FFD / 32, DD / 32), 256, 0, stream>>>(
            W1 + (size_t)e * DD * FFD, W1T + (size_t)e * FFD * DD, DD, FFD, DD);
        transpose_convert_kernel<<<dim3(DD / 32, FFD / 32), 256, 0, stream>>>(
            W2 + (size_t)e * FFD * DD, W2T + (size_t)e * FFD, FFD, DD, NE * FFD);
    }

    // ---- QKV (batched, N=2304) -> bf16 Q,K [B,H,T,64], V^T [B,H,64,T] ----
    gemm_bt_kernel<<<dim3(2304 / 128, NTOK / 128, 1), 256, 0, stream>>>(
        src_h, DD, 0, WqkvH, DD, 0, DD, 0,
        nullptr, Qh, Kh, VTh, 0, 0, bqkv, 0, nullptr, nullptr);

    // ---- attention (MFMA) ----
    attn_mfma_kernel<<<dim3(TT / 32, BB * HH), 256, 0, stream>>>(
        Qh, Kh, VTh, gam, attn_h);

    // ---- Wo projection + residual ----
    gemm_bt_kernel<<<dim3(DD / 128, NTOK / 128, 1), 256, 0, stream>>>(
        attn_h, DD, 0, WoH, DD, 0, DD, 1,
        r1, nullptr, nullptr, nullptr, DD, 0, bo, 0, src, nullptr);

    // ---- LN1 ----
    ln_kernel<<<NTOK, 256, 0, stream>>>(r1, nullptr, nullptr, nullptr, nullptr,
                                        ln1g, ln1b, x, xh, 0);

    // ---- gate ----
    gate_kernel<<<NTOK / 4, 256, 0, stream>>>(x, Wg, bg, comb);

    // ---- FF1 (all experts, comb folded in) ----
    gemm_bt_kernel<<<dim3(FFD / 128, NTOK / 128, NE), 256, 0, stream>>>(
        xh, DD, 0, W1T, DD, (long)FFD * DD, DD, 2,
        nullptr, hb, nullptr, nullptr, NE * FFD, FFD, b1, FFD, nullptr, comb);

    // ---- FF2 (split over experts -> 4 partial buffers) ----
    gemm_bt_kernel<<<dim3(DD / 128, NTOK / 128, NE), 256, 0, stream>>>(
        hb, NE * FFD, FFD, W2T, NE * FFD, FFD, FFD, 3,
        ffp, nullptr, nullptr, nullptr, DD, (long)NTOK * DD, b2, DD, nullptr, comb);

    // ---- LN2 (sums partials inline) ----
    ln_kernel<<<NTOK, 256, 0, stream>>>(
        x, ffp, ffp + (size_t)NTOK * DD, ffp + 2 * (size_t)NTOK * DD,
        ffp + 3 * (size_t)NTOK * DD,
        ln2g, ln2b, (float*)d_out, nullptr, 1);
}

// Round 5
// 528.550 us; speedup vs baseline: 3.6479x; 1.0218x over previous
//
#include <hip/hip_runtime.h>

typedef unsigned short u16;
typedef short bf16x8 __attribute__((ext_vector_type(8)));
typedef float f32x4 __attribute__((ext_vector_type(4)));

#define BB 2
#define TT 1024
#define DD 768
#define HH 12
#define HD 64
#define FFD 3072
#define NE 4
#define NTOK (BB*TT)

#define MFMA16(a, b, c) __builtin_amdgcn_mfma_f32_16x16x32_bf16((a), (b), (c), 0, 0, 0)

#define ASYNC16(gsrc, ldst)                                                    \
    __builtin_amdgcn_global_load_lds(                                          \
        (const __attribute__((address_space(1))) void*)(gsrc),                 \
        (__attribute__((address_space(3))) void*)(ldst), 16, 0, 0)

__device__ __forceinline__ float us2f(u16 u) {
    return __uint_as_float(((unsigned int)u) << 16);
}
__device__ __forceinline__ u16 f2us(float f) {
    unsigned int x = __float_as_uint(f);
    x += 0x7fffu + ((x >> 16) & 1u);
    return (u16)(x >> 16);
}

// ---------------------------------------------------------------------------
// Flat fp32 -> bf16 convert. n8 = n/8 work items.
// ---------------------------------------------------------------------------
__global__ __launch_bounds__(256) void convert_kernel(
    const float* __restrict__ in, u16* __restrict__ out, int n8)
{
    int i = blockIdx.x * 256 + threadIdx.x;
    if (i >= n8) return;
    const float4* p = reinterpret_cast<const float4*>(in) + (size_t)i * 2;
    float4 a = p[0], b = p[1];
    u16 o[8] = {f2us(a.x), f2us(a.y), f2us(a.z), f2us(a.w),
                f2us(b.x), f2us(b.y), f2us(b.z), f2us(b.w)};
    *reinterpret_cast<uint4*>(out + (size_t)i * 8) = *reinterpret_cast<uint4*>(o);
}

// ---------------------------------------------------------------------------
// Transpose + convert: src [R,C] fp32 row-major -> dst bf16, dst[c*dstStride+r].
// ---------------------------------------------------------------------------
__global__ __launch_bounds__(256) void transpose_convert_kernel(
    const float* __restrict__ src, u16* __restrict__ dst,
    int R, int C, int dstStride)
{
    __shared__ float tile[32][33];
    const int c0 = blockIdx.x * 32, r0 = blockIdx.y * 32;
    const int tx = threadIdx.x & 31, ty = threadIdx.x >> 5;
    #pragma unroll
    for (int it = 0; it < 4; it++) {
        int r = ty + it * 8;
        tile[r][tx] = src[(size_t)(r0 + r) * C + c0 + tx];
    }
    __syncthreads();
    #pragma unroll
    for (int it = 0; it < 4; it++) {
        int c = ty + it * 8;
        dst[(size_t)(c0 + c) * dstStride + r0 + tx] = f2us(tile[tx][c]);
    }
}

// ---------------------------------------------------------------------------
// bf16 MFMA GEMM: C[M,N] = A[M,K] * Bt[N,K]^T  (both row-major, K-contiguous)
// 128x128 tile, 4 waves, 16x16x32 MFMA, fp32 accum.
// Staging: global_load_lds 16B into unpadded [128][32] u16 LDS; XOR column-
// group swizzle (group ^= (row>>1)&3) applied at the global-source side so
// both HW LDS writes and ds_read_b128 frag reads are bank-balanced.
// modes:
//  0 QKV:  y=acc+biasF[n]; bf16 scatter: Q,K -> [B,H,T,64]; V -> VT [B,H,64,T]
//  1 Wo:   y=acc+biasF[n]+src[m*N+n] -> outF fp32 [M,N]
//  2 FF1:  y=relu(acc+biasF[z*biasZ+n])*comb[m*4+z] -> bf16 outH[m*ldc+cZ*z+n]
//  3 FF2:  y=acc+comb[m*4+z]*biasF[z*biasZ+n] -> fp32 outF[z*cZ+m*ldc+n]
// mswap: if 1, blockIdx.x indexes M (m-fastest dispatch for B-tile L2 reuse).
// ---------------------------------------------------------------------------
__global__ __launch_bounds__(256) void gemm_bt_kernel(
    const u16* __restrict__ A, int lda, long aZ,
    const u16* __restrict__ Bt, int ldb, long bZ,
    int K, int mode, int mswap,
    float* __restrict__ outF, u16* __restrict__ outH,
    u16* __restrict__ outH2, u16* __restrict__ outH3,
    int ldc, long cZ,
    const float* __restrict__ biasF, int biasZ,
    const float* __restrict__ src, const float* __restrict__ comb)
{
    __shared__ __align__(16) u16 As[128 * 32];
    __shared__ __align__(16) u16 Bs[128 * 32];
    const int tid = threadIdx.x;
    const int z = blockIdx.z;
    const int bx = mswap ? blockIdx.y : blockIdx.x;
    const int by = mswap ? blockIdx.x : blockIdx.y;
    const int m0 = by * 128, n0 = bx * 128;
    const u16* Ab = A + (size_t)z * aZ;
    const u16* Bb = Bt + (size_t)z * bZ;

    const int wave = tid >> 6, lane = tid & 63;
    const int wm = (wave & 1) * 64, wn = (wave >> 1) * 64;
    const int fm = lane & 15;
    const int g  = lane >> 4;

    // staging: wave w covers tile rows [w*32, w*32+32), 2 instrs per operand
    const int lrow = lane >> 2;             // 0..15
    const int lgrp = lane & 3;              // 0..3
    const int cg   = (lgrp ^ ((lrow >> 1) & 3)) * 8;   // swizzled col group
    const int r0   = wave * 32 + lrow;
    const u16* aG0 = Ab + (size_t)(m0 + r0) * lda + cg;
    const u16* aG1 = Ab + (size_t)(m0 + r0 + 16) * lda + cg;
    const u16* bG0 = Bb + (size_t)(n0 + r0) * ldb + cg;
    const u16* bG1 = Bb + (size_t)(n0 + r0 + 16) * ldb + cg;
    u16* aL0 = &As[(wave * 32) * 32];
    u16* aL1 = &As[(wave * 32 + 16) * 32];
    u16* bL0 = &Bs[(wave * 32) * 32];
    u16* bL1 = &Bs[(wave * 32 + 16) * 32];

    // fragment LDS addresses (loop-invariant); read swizzle mirrors store
    const int sw8 = ((fm >> 1) & 3) * 8;
    const u16* pa[4]; const u16* pb[4];
    #pragma unroll
    for (int i = 0; i < 4; i++) {
        pa[i] = &As[(wm + i * 16 + fm) * 32 + ((g * 8) ^ sw8)];
        pb[i] = &Bs[(wn + i * 16 + fm) * 32 + ((g * 8) ^ sw8)];
    }

    f32x4 acc[4][4] = {};

    for (int k0 = 0; k0 < K; k0 += 32) {
        ASYNC16(aG0 + k0, aL0);
        ASYNC16(aG1 + k0, aL1);
        ASYNC16(bG0 + k0, bL0);
        ASYNC16(bG1 + k0, bL1);
        __syncthreads();

        bf16x8 af[4], bf[4];
        #pragma unroll
        for (int i = 0; i < 4; i++) af[i] = *reinterpret_cast<const bf16x8*>(pa[i]);
        #pragma unroll
        for (int j = 0; j < 4; j++) bf[j] = *reinterpret_cast<const bf16x8*>(pb[j]);
        #pragma unroll
        for (int i = 0; i < 4; i++)
            #pragma unroll
            for (int j = 0; j < 4; j++)
                acc[i][j] = MFMA16(af[i], bf[j], acc[i][j]);
        __syncthreads();
    }

    // C/D layout: col = lane&15, row = (lane>>4)*4 + reg   [m89-verified]
    const int cn = lane & 15, cr = (lane >> 4) * 4;
    #pragma unroll
    for (int i = 0; i < 4; i++) {
        #pragma unroll
        for (int j = 0; j < 4; j++) {
            const int n = n0 + wn + j * 16 + cn;
            #pragma unroll
            for (int r = 0; r < 4; r++) {
                const int m = m0 + wm + i * 16 + cr + r;
                float y = acc[i][j][r];
                if (mode == 0) {
                    y += biasF[n];
                    int which = (n >= 1536) ? 2 : (n >= 768 ? 1 : 0);
                    int nn = n - which * 768;
                    int bb = m >> 10, t = m & 1023;
                    int hh = nn >> 6, d = nn & 63;
                    if (which == 0)
                        outH[(((size_t)(bb * HH + hh) * TT + t) << 6) + d] = f2us(y);
                    else if (which == 1)
                        outH2[(((size_t)(bb * HH + hh) * TT + t) << 6) + d] = f2us(y);
                    else
                        outH3[(((size_t)(bb * HH + hh) * HD + d) << 10) + t] = f2us(y);
                } else if (mode == 1) {
                    size_t idx = (size_t)m * ldc + n;
                    outF[idx] = y + biasF[n] + src[idx];
                } else if (mode == 2) {
                    y = fmaxf(y + biasF[(size_t)z * biasZ + n], 0.f) * comb[m * NE + z];
                    outH[(size_t)m * ldc + (size_t)z * cZ + n] = f2us(y);
                } else {
                    y += comb[m * NE + z] * biasF[(size_t)z * biasZ + n];
                    outF[(size_t)z * cZ + (size_t)m * ldc + n] = y;
                }
            }
        }
    }
}

// ---------------------------------------------------------------------------
// MFMA attention. Block = (qt 32 rows, b*12+h). 4 waves.
// Phase 1: S[32][1024] in accumulators (wave w covers cols w*256..+256).
// zscore is scale-invariant: a = gamma/(std_ddof1(S)+EPS_Z/0.125); shift
// cancels in softmax; cm = max(a*S) for stability.
// Phase 2: P bf16 in LDS; O = P*V via MFMA (V pre-transposed [B,H,64,T]).
// ---------------------------------------------------------------------------
#define PSTR 1032  // u16 stride: byte stride 2064 (16B aligned), dw 516 ≡ 4 mod 8 -> conflict-free b128
__global__ __launch_bounds__(256, 2) void attn_mfma_kernel(
    const u16* __restrict__ Qh, const u16* __restrict__ Kh,
    const u16* __restrict__ VT, const float* __restrict__ gamma_p,
    u16* __restrict__ attn_out)
{
    __shared__ __align__(16) u16 P[32 * PSTR];
    __shared__ float wred[4][32][4];
    __shared__ float dred[4][32];
    __shared__ float aArr[32], cmArr[32], dinvArr[32];

    const int qt = blockIdx.x, bh = blockIdx.y;
    const int b = bh / HH, h = bh - b * HH;
    const int tid = threadIdx.x, wave = tid >> 6, lane = tid & 63;
    const int g = lane >> 4, fm = lane & 15;
    const float gamma = gamma_p[0];
    const int m0 = qt * 32;
    const u16* Qp = Qh + (size_t)bh * TT * HD;
    const u16* Kp = Kh + (size_t)bh * TT * HD;
    const u16* Vp = VT + (size_t)bh * HD * TT;

    bf16x8 af[2][2];
    #pragma unroll
    for (int mi = 0; mi < 2; mi++)
        #pragma unroll
        for (int ks = 0; ks < 2; ks++)
            af[mi][ks] = *reinterpret_cast<const bf16x8*>(
                Qp + (size_t)(m0 + mi * 16 + fm) * HD + ks * 32 + g * 8);

    const int n0w = wave * 256;
    f32x4 acc[16][2] = {};
    #pragma unroll
    for (int nj = 0; nj < 16; nj++) {
        const u16* kp = Kp + (size_t)(n0w + nj * 16 + fm) * HD + g * 8;
        bf16x8 b0 = *reinterpret_cast<const bf16x8*>(kp);
        bf16x8 b1 = *reinterpret_cast<const bf16x8*>(kp + 32);
        acc[nj][0] = MFMA16(af[0][0], b0, acc[nj][0]);
        acc[nj][0] = MFMA16(af[0][1], b1, acc[nj][0]);
        acc[nj][1] = MFMA16(af[1][0], b0, acc[nj][1]);
        acc[nj][1] = MFMA16(af[1][1], b1, acc[nj][1]);
    }

    #pragma unroll
    for (int mi = 0; mi < 2; mi++) {
        #pragma unroll
        for (int r = 0; r < 4; r++) {
            float s1 = 0.f, s2 = 0.f, mx = -3.4e38f, mn = 3.4e38f;
            #pragma unroll
            for (int nj = 0; nj < 16; nj++) {
                float v = acc[nj][mi][r];
                s1 += v; s2 = fmaf(v, v, s2);
                mx = fmaxf(mx, v); mn = fminf(mn, v);
            }
            #pragma unroll
            for (int msk = 1; msk < 16; msk <<= 1) {
                s1 += __shfl_xor(s1, msk);
                s2 += __shfl_xor(s2, msk);
                mx = fmaxf(mx, __shfl_xor(mx, msk));
                mn = fminf(mn, __shfl_xor(mn, msk));
            }
            if (fm == 0) {
                int row = mi * 16 + g * 4 + r;
                wred[wave][row][0] = s1; wred[wave][row][1] = s2;
                wred[wave][row][2] = mx; wred[wave][row][3] = mn;
            }
        }
    }
    __syncthreads();
    if (tid < 32) {
        float s1 = 0.f, s2 = 0.f, mx = -3.4e38f, mn = 3.4e38f;
        #pragma unroll
        for (int w = 0; w < 4; w++) {
            s1 += wred[w][tid][0]; s2 += wred[w][tid][1];
            mx = fmaxf(mx, wred[w][tid][2]); mn = fminf(mn, wred[w][tid][3]);
        }
        float var = (s2 - s1 * s1 * (1.f / TT)) * (1.f / (TT - 1));
        var = fmaxf(var, 0.f);
        float a = gamma / (sqrtf(var) + 8e-5f);
        aArr[tid] = a;
        cmArr[tid] = (a >= 0.f) ? a * mx : a * mn;
    }
    __syncthreads();

    #pragma unroll
    for (int mi = 0; mi < 2; mi++) {
        #pragma unroll
        for (int r = 0; r < 4; r++) {
            const int row = mi * 16 + g * 4 + r;
            const float a = aArr[row], cm = cmArr[row];
            float dp = 0.f;
            #pragma unroll
            for (int nj = 0; nj < 16; nj++) {
                float p = __expf(fmaf(a, acc[nj][mi][r], -cm));
                u16 pb = f2us(p);
                dp += us2f(pb);
                P[row * PSTR + n0w + nj * 16 + fm] = pb;
            }
            #pragma unroll
            for (int msk = 1; msk < 16; msk <<= 1) dp += __shfl_xor(dp, msk);
            if (fm == 0) dred[wave][row] = dp;
        }
    }
    __syncthreads();
    if (tid < 32)
        dinvArr[tid] = 1.f / (dred[0][tid] + dred[1][tid] + dred[2][tid] + dred[3][tid]);
    __syncthreads();

    f32x4 oacc[2] = {};
    #pragma unroll 4
    for (int ks = 0; ks < 32; ks++) {
        bf16x8 bv = *reinterpret_cast<const bf16x8*>(
            Vp + (size_t)(wave * 16 + fm) * TT + ks * 32 + g * 8);
        bf16x8 a0 = *reinterpret_cast<const bf16x8*>(&P[(size_t)fm * PSTR + ks * 32 + g * 8]);
        bf16x8 a1 = *reinterpret_cast<const bf16x8*>(&P[(size_t)(16 + fm) * PSTR + ks * 32 + g * 8]);
        oacc[0] = MFMA16(a0, bv, oacc[0]);
        oacc[1] = MFMA16(a1, bv, oacc[1]);
    }
    #pragma unroll
    for (int mi = 0; mi < 2; mi++) {
        #pragma unroll
        for (int r = 0; r < 4; r++) {
            int row = mi * 16 + g * 4 + r;
            int t = m0 + row;
            attn_out[((size_t)(b * TT + t)) * DD + h * HD + wave * 16 + fm] =
                f2us(oacc[mi][r] * dinvArr[row]);
        }
    }
}

// ---------------------------------------------------------------------------
// LayerNorm over D=768.
// mode 0: in1 -> outF fp32 + outH bf16.   mode 1: in1+p0+p1+p2+p3 -> outF.
// ---------------------------------------------------------------------------
__global__ __launch_bounds__(256) void ln_kernel(
    const float* __restrict__ in1,
    const float* __restrict__ p0, const float* __restrict__ p1,
    const float* __restrict__ p2, const float* __restrict__ p3,
    const float* __restrict__ g, const float* __restrict__ bta,
    float* __restrict__ outF, u16* __restrict__ outH, int mode)
{
    const int row = blockIdx.x, tid = threadIdx.x;
    __shared__ float red[256];
    const size_t base = (size_t)row * DD;
    float v[3];
    #pragma unroll
    for (int i = 0; i < 3; i++) {
        int c = tid + i * 256;
        float t = in1[base + c];
        if (mode == 1) t += p0[base + c] + p1[base + c] + p2[base + c] + p3[base + c];
        v[i] = t;
    }
    float s = v[0] + v[1] + v[2];
    red[tid] = s; __syncthreads();
    #pragma unroll
    for (int o = 128; o > 0; o >>= 1) { if (tid < o) red[tid] += red[tid + o]; __syncthreads(); }
    const float mean = red[0] * (1.f / 768.f);
    __syncthreads();
    float qv = 0.f;
    #pragma unroll
    for (int i = 0; i < 3; i++) { float d = v[i] - mean; qv += d * d; }
    red[tid] = qv; __syncthreads();
    #pragma unroll
    for (int o = 128; o > 0; o >>= 1) { if (tid < o) red[tid] += red[tid + o]; __syncthreads(); }
    const float var = red[0] * (1.f / 768.f);
    const float rs = rsqrtf(var + 1e-5f);
    #pragma unroll
    for (int i = 0; i < 3; i++) {
        int c = tid + i * 256;
        float o = (v[i] - mean) * rs * g[c] + bta[c];
        outF[base + c] = o;
        if (mode == 0) outH[base + c] = f2us(o);
    }
}

// ---------------------------------------------------------------------------
// Gate: one wave per token. softmax over E=4, top-2 -> combine weights.
// ---------------------------------------------------------------------------
__global__ __launch_bounds__(256) void gate_kernel(
    const float* __restrict__ x, const float* __restrict__ Wg,
    const float* __restrict__ bg, float* __restrict__ comb)
{
    const int wid = threadIdx.x >> 6, lane = threadIdx.x & 63;
    const int t = blockIdx.x * 4 + wid;
    const float* xr = x + (size_t)t * DD;
    float g[NE];
    #pragma unroll
    for (int e = 0; e < NE; e++) {
        float p = 0.f;
        for (int d = lane; d < DD; d += 64) p += xr[d] * Wg[e * DD + d];
        #pragma unroll
        for (int off = 32; off > 0; off >>= 1) p += __shfl_down(p, off, 64);
        g[e] = p;
    }
    if (lane == 0) {
        float m = -1e30f;
        #pragma unroll
        for (int e = 0; e < NE; e++) { g[e] += bg[e]; m = fmaxf(m, g[e]); }
        float ex[NE], s = 0.f;
        #pragma unroll
        for (int e = 0; e < NE; e++) { ex[e] = __expf(g[e] - m); s += ex[e]; }
        #pragma unroll
        for (int e = 0; e < NE; e++) ex[e] /= s;
        int e1 = 0;
        #pragma unroll
        for (int e = 1; e < NE; e++) if (ex[e] > ex[e1]) e1 = e;
        int e2 = -1;
        #pragma unroll
        for (int e = 0; e < NE; e++) if (e != e1 && (e2 < 0 || ex[e] > ex[e2])) e2 = e;
        float c[NE] = {0.f, 0.f, 0.f, 0.f};
        c[e1] = ex[e1]; c[e2] = ex[e2];
        #pragma unroll
        for (int e = 0; e < NE; e++) comb[(size_t)t * NE + e] = c[e];
    }
}

extern "C" void kernel_launch(void* const* d_in, const int* in_sizes, int n_in,
                              void* d_out, int out_size, void* d_ws, size_t ws_size,
                              hipStream_t stream)
{
    const float* src  = (const float*)d_in[0];
    const float* Wq   = (const float*)d_in[2];  const float* bq = (const float*)d_in[3];
    const float* Wk   = (const float*)d_in[4];  const float* bk = (const float*)d_in[5];
    const float* Wv   = (const float*)d_in[6];  const float* bv = (const float*)d_in[7];
    const float* Wo   = (const float*)d_in[8];  const float* bo = (const float*)d_in[9];
    const float* gam  = (const float*)d_in[10];
    const float* ln1g = (const float*)d_in[11]; const float* ln1b = (const float*)d_in[12];
    const float* ln2g = (const float*)d_in[13]; const float* ln2b = (const float*)d_in[14];
    const float* Wg   = (const float*)d_in[15]; const float* bg = (const float*)d_in[16];
    const float* W1   = (const float*)d_in[17]; const float* b1 = (const float*)d_in[18];
    const float* W2   = (const float*)d_in[19]; const float* b2 = (const float*)d_in[20];
    (void)ws_size; (void)in_sizes; (void)n_in; (void)out_size;

    char* ws = (char*)d_ws;
    // persistent regions
    u16*   W1T  = (u16*)(ws);                              // 18,874,368 B
    u16*   W2T  = (u16*)(ws + 18874368);                   // 18,874,368 B
    u16*   hb   = (u16*)(ws + 37748736);                   // 50,331,648 B
    float* x    = (float*)(ws + 88080384);                 //  6,291,456 B
    u16*   xh   = (u16*)(ws + 94371840);                   //  3,145,728 B
    float* ffp  = (float*)(ws + 97517568);                 // 25,165,824 B (4 partials)
    float* comb = (float*)(ws + 122683392);                //     32,768 B
    float* bqkv = (float*)(ws + 122716160);                //      9,216 B
    // aliases inside hb region (all dead before FF1 writes hb)
    char* H = ws + 37748736;
    u16*   Qh     = (u16*)(H);                             //  3,145,728 B
    u16*   Kh     = (u16*)(H + 3145728);                   //  3,145,728 B
    u16*   VTh    = (u16*)(H + 6291456);                   //  3,145,728 B
    u16*   src_h  = (u16*)(H + 9437184);                   //  3,145,728 B
    u16*   attn_h = (u16*)(H + 12582912);                  //  3,145,728 B
    u16*   WqkvH  = (u16*)(H + 15728640);                  //  3,538,944 B
    u16*   WoH    = (u16*)(H + 19267584);                  //  1,179,648 B
    float* r1     = (float*)(H + 20447232);                //  6,291,456 B

    const int DW = DD * DD;  // 589824

    // ---- weight/activation conversions ----
    convert_kernel<<<(NTOK * DD / 8 + 255) / 256, 256, 0, stream>>>(src, src_h, NTOK * DD / 8);
    convert_kernel<<<(DW / 8 + 255) / 256, 256, 0, stream>>>(Wq, WqkvH, DW / 8);
    convert_kernel<<<(DW / 8 + 255) / 256, 256, 0, stream>>>(Wk, WqkvH + DW, DW / 8);
    convert_kernel<<<(DW / 8 + 255) / 256, 256, 0, stream>>>(Wv, WqkvH + 2 * DW, DW / 8);
    convert_kernel<<<(DW / 8 + 255) / 256, 256, 0, stream>>>(Wo, WoH, DW / 8);
    hipMemcpyAsync(bqkv, bq, DD * 4, hipMemcpyDeviceToDevice, stream);
    hipMemcpyAsync(bqkv + DD, bk, DD * 4, hipMemcpyDeviceToDevice, stream);
    hipMemcpyAsync(bqkv + 2 * DD, bv, DD * 4, hipMemcpyDeviceToDevice, stream);
    for (int e = 0; e < NE; e++) {
        transpose_convert_kernel<<<dim3(FFD / 32, DD / 32), 256, 0, stream>>>(
            W1 + (size_t)e * DD * FFD, W1T + (size_t)e * FFD * DD, DD, FFD, DD);
        transpose_convert_kernel<<<dim3(DD / 32, FFD / 32), 256, 0, stream>>>(
            W2 + (size_t)e * FFD * DD, W2T + (size_t)e * FFD, FFD, DD, NE * FFD);
    }

    // ---- QKV (batched, N=2304) -> bf16 Q,K [B,H,T,64], V^T [B,H,64,T] ----
    gemm_bt_kernel<<<dim3(2304 / 128, NTOK / 128, 1), 256, 0, stream>>>(
        src_h, DD, 0, WqkvH, DD, 0, DD, 0, 0,
        nullptr, Qh, Kh, VTh, 0, 0, bqkv, 0, nullptr, nullptr);

    // ---- attention (MFMA) ----
    attn_mfma_kernel<<<dim3(TT / 32, BB * HH), 256, 0, stream>>>(
        Qh, Kh, VTh, gam, attn_h);

    // ---- Wo projection + residual ----
    gemm_bt_kernel<<<dim3(DD / 128, NTOK / 128, 1), 256, 0, stream>>>(
        attn_h, DD, 0, WoH, DD, 0, DD, 1, 0,
        r1, nullptr, nullptr, nullptr, DD, 0, bo, 0, src, nullptr);

    // ---- LN1 ----
    ln_kernel<<<NTOK, 256, 0, stream>>>(r1, nullptr, nullptr, nullptr, nullptr,
                                        ln1g, ln1b, x, xh, 0);

    // ---- gate ----
    gate_kernel<<<NTOK / 4, 256, 0, stream>>>(x, Wg, bg, comb);

    // ---- FF1 (all experts, comb folded in; m-fastest grid for W1-tile reuse) ----
    gemm_bt_kernel<<<dim3(NTOK / 128, FFD / 128, NE), 256, 0, stream>>>(
        xh, DD, 0, W1T, DD, (long)FFD * DD, DD, 2, 1,
        nullptr, hb, nullptr, nullptr, NE * FFD, FFD, b1, FFD, nullptr, comb);

    // ---- FF2 (split over experts -> 4 partial buffers) ----
    gemm_bt_kernel<<<dim3(DD / 128, NTOK / 128, NE), 256, 0, stream>>>(
        hb, NE * FFD, FFD, W2T, NE * FFD, FFD, FFD, 3, 0,
        ffp, nullptr, nullptr, nullptr, DD, (long)NTOK * DD, b2, DD, nullptr, comb);

    // ---- LN2 (sums partials inline) ----
    ln_kernel<<<NTOK, 256, 0, stream>>>(
        x, ffp, ffp + (size_t)NTOK * DD, ffp + 2 * (size_t)NTOK * DD,
        ffp + 3 * (size_t)NTOK * DD,
        ln2g, ln2b, (float*)d_out, nullptr, 1);
}

// Round 6
// 511.235 us; speedup vs baseline: 3.7714x; 1.0339x over previous
//
#include <hip/hip_runtime.h>

typedef unsigned short u16;
typedef short bf16x8 __attribute__((ext_vector_type(8)));
typedef float f32x4 __attribute__((ext_vector_type(4)));

#define BB 2
#define TT 1024
#define DD 768
#define HH 12
#define HD 64
#define FFD 3072
#define NE 4
#define NTOK (BB*TT)

#define MFMA16(a, b, c) __builtin_amdgcn_mfma_f32_16x16x32_bf16((a), (b), (c), 0, 0, 0)

#define ASYNC16(gsrc, ldst)                                                    \
    __builtin_amdgcn_global_load_lds(                                          \
        (const __attribute__((address_space(1))) void*)(gsrc),                 \
        (__attribute__((address_space(3))) void*)(ldst), 16, 0, 0)

__device__ __forceinline__ float us2f(u16 u) {
    return __uint_as_float(((unsigned int)u) << 16);
}
__device__ __forceinline__ u16 f2us(float f) {
    unsigned int x = __float_as_uint(f);
    x += 0x7fffu + ((x >> 16) & 1u);
    return (u16)(x >> 16);
}

// ---------------------------------------------------------------------------
// Flat fp32 -> bf16 convert. n8 = n/8 work items.
// ---------------------------------------------------------------------------
__global__ __launch_bounds__(256) void convert_kernel(
    const float* __restrict__ in, u16* __restrict__ out, int n8)
{
    int i = blockIdx.x * 256 + threadIdx.x;
    if (i >= n8) return;
    const float4* p = reinterpret_cast<const float4*>(in) + (size_t)i * 2;
    float4 a = p[0], b = p[1];
    u16 o[8] = {f2us(a.x), f2us(a.y), f2us(a.z), f2us(a.w),
                f2us(b.x), f2us(b.y), f2us(b.z), f2us(b.w)};
    *reinterpret_cast<uint4*>(out + (size_t)i * 8) = *reinterpret_cast<uint4*>(o);
}

// ---------------------------------------------------------------------------
// Transpose + convert: src [R,C] fp32 row-major -> dst bf16, dst[c*dstStride+r].
// ---------------------------------------------------------------------------
__global__ __launch_bounds__(256) void transpose_convert_kernel(
    const float* __restrict__ src, u16* __restrict__ dst,
    int R, int C, int dstStride)
{
    __shared__ float tile[32][33];
    const int c0 = blockIdx.x * 32, r0 = blockIdx.y * 32;
    const int tx = threadIdx.x & 31, ty = threadIdx.x >> 5;
    #pragma unroll
    for (int it = 0; it < 4; it++) {
        int r = ty + it * 8;
        tile[r][tx] = src[(size_t)(r0 + r) * C + c0 + tx];
    }
    __syncthreads();
    #pragma unroll
    for (int it = 0; it < 4; it++) {
        int c = ty + it * 8;
        dst[(size_t)(c0 + c) * dstStride + r0 + tx] = f2us(tile[tx][c]);
    }
}

// ---------------------------------------------------------------------------
// bf16 MFMA GEMM: C[M,N] = A[M,K] * Bt[N,K]^T  (both row-major, K-contiguous)
// 128x128 tile, 4 waves, 16x16x32 MFMA, fp32 accum.
// Staging: global_load_lds 16B into unpadded [128][32] u16 LDS; XOR column-
// group swizzle (group ^= (row>>1)&3) applied at the global-source side so
// both HW LDS writes and ds_read_b128 frag reads are bank-balanced.
// modes:
//  0 QKV:  y=acc+biasF[n]; bf16 scatter: Q,K -> [B,H,T,64]; V -> VT [B,H,64,T]
//  1 Wo:   y=acc+biasF[n]+src[m*N+n] -> outF fp32 [M,N]
//  2 FF1:  y=relu(acc+biasF[z*biasZ+n])*comb[m*4+z] -> bf16 outH[m*ldc+cZ*z+n]
//  3 FF2 split-K: plain store of partial y to slab z:
//         z<4 -> outF + z*cZ; z in 4..6 -> (float*)outH + (z-4)*cZ; z==7 -> (float*)outH2
// mswap: if 1, blockIdx.x indexes M (m-fastest dispatch for B-tile L2 reuse).
// ---------------------------------------------------------------------------
__global__ __launch_bounds__(256) void gemm_bt_kernel(
    const u16* __restrict__ A, int lda, long aZ,
    const u16* __restrict__ Bt, int ldb, long bZ,
    int K, int mode, int mswap,
    float* __restrict__ outF, u16* __restrict__ outH,
    u16* __restrict__ outH2, u16* __restrict__ outH3,
    int ldc, long cZ,
    const float* __restrict__ biasF, int biasZ,
    const float* __restrict__ src, const float* __restrict__ comb)
{
    __shared__ __align__(16) u16 As[128 * 32];
    __shared__ __align__(16) u16 Bs[128 * 32];
    const int tid = threadIdx.x;
    const int z = blockIdx.z;
    const int bx = mswap ? blockIdx.y : blockIdx.x;
    const int by = mswap ? blockIdx.x : blockIdx.y;
    const int m0 = by * 128, n0 = bx * 128;
    const u16* Ab = A + (size_t)z * aZ;
    const u16* Bb = Bt + (size_t)z * bZ;

    const int wave = tid >> 6, lane = tid & 63;
    const int wm = (wave & 1) * 64, wn = (wave >> 1) * 64;
    const int fm = lane & 15;
    const int g  = lane >> 4;

    // staging: wave w covers tile rows [w*32, w*32+32), 2 instrs per operand
    const int lrow = lane >> 2;             // 0..15
    const int lgrp = lane & 3;              // 0..3
    const int cg   = (lgrp ^ ((lrow >> 1) & 3)) * 8;   // swizzled col group
    const int r0   = wave * 32 + lrow;
    const u16* aG0 = Ab + (size_t)(m0 + r0) * lda + cg;
    const u16* aG1 = Ab + (size_t)(m0 + r0 + 16) * lda + cg;
    const u16* bG0 = Bb + (size_t)(n0 + r0) * ldb + cg;
    const u16* bG1 = Bb + (size_t)(n0 + r0 + 16) * ldb + cg;
    u16* aL0 = &As[(wave * 32) * 32];
    u16* aL1 = &As[(wave * 32 + 16) * 32];
    u16* bL0 = &Bs[(wave * 32) * 32];
    u16* bL1 = &Bs[(wave * 32 + 16) * 32];

    // fragment LDS addresses (loop-invariant); read swizzle mirrors store
    const int sw8 = ((fm >> 1) & 3) * 8;
    const u16* pa[4]; const u16* pb[4];
    #pragma unroll
    for (int i = 0; i < 4; i++) {
        pa[i] = &As[(wm + i * 16 + fm) * 32 + ((g * 8) ^ sw8)];
        pb[i] = &Bs[(wn + i * 16 + fm) * 32 + ((g * 8) ^ sw8)];
    }

    f32x4 acc[4][4] = {};

    for (int k0 = 0; k0 < K; k0 += 32) {
        ASYNC16(aG0 + k0, aL0);
        ASYNC16(aG1 + k0, aL1);
        ASYNC16(bG0 + k0, bL0);
        ASYNC16(bG1 + k0, bL1);
        __syncthreads();

        bf16x8 af[4], bf[4];
        #pragma unroll
        for (int i = 0; i < 4; i++) af[i] = *reinterpret_cast<const bf16x8*>(pa[i]);
        #pragma unroll
        for (int j = 0; j < 4; j++) bf[j] = *reinterpret_cast<const bf16x8*>(pb[j]);
        #pragma unroll
        for (int i = 0; i < 4; i++)
            #pragma unroll
            for (int j = 0; j < 4; j++)
                acc[i][j] = MFMA16(af[i], bf[j], acc[i][j]);
        __syncthreads();
    }

    // C/D layout: col = lane&15, row = (lane>>4)*4 + reg   [m89-verified]
    const int cn = lane & 15, cr = (lane >> 4) * 4;
    #pragma unroll
    for (int i = 0; i < 4; i++) {
        #pragma unroll
        for (int j = 0; j < 4; j++) {
            const int n = n0 + wn + j * 16 + cn;
            #pragma unroll
            for (int r = 0; r < 4; r++) {
                const int m = m0 + wm + i * 16 + cr + r;
                float y = acc[i][j][r];
                if (mode == 0) {
                    y += biasF[n];
                    int which = (n >= 1536) ? 2 : (n >= 768 ? 1 : 0);
                    int nn = n - which * 768;
                    int bb = m >> 10, t = m & 1023;
                    int hh = nn >> 6, d = nn & 63;
                    if (which == 0)
                        outH[(((size_t)(bb * HH + hh) * TT + t) << 6) + d] = f2us(y);
                    else if (which == 1)
                        outH2[(((size_t)(bb * HH + hh) * TT + t) << 6) + d] = f2us(y);
                    else
                        outH3[(((size_t)(bb * HH + hh) * HD + d) << 10) + t] = f2us(y);
                } else if (mode == 1) {
                    size_t idx = (size_t)m * ldc + n;
                    outF[idx] = y + biasF[n] + src[idx];
                } else if (mode == 2) {
                    y = fmaxf(y + biasF[(size_t)z * biasZ + n], 0.f) * comb[m * NE + z];
                    outH[(size_t)m * ldc + (size_t)z * cZ + n] = f2us(y);
                } else {
                    float* base = (z < 4) ? (outF + (size_t)z * cZ)
                                : (z < 7) ? ((float*)outH + (size_t)(z - 4) * cZ)
                                          : (float*)outH2;
                    base[(size_t)m * ldc + n] = y;
                }
            }
        }
    }
}

// ---------------------------------------------------------------------------
// MFMA attention. Block = (qt 32 rows, b*12+h). 4 waves.
// Phase 1: S[32][1024] in accumulators (wave w covers cols w*256..+256).
// zscore is scale-invariant: a = gamma/(std_ddof1(S)+EPS_Z/0.125); shift
// cancels in softmax; cm = max(a*S) for stability.
// Phase 2: P bf16 in LDS; O = P*V via MFMA (V pre-transposed [B,H,64,T]).
// ---------------------------------------------------------------------------
#define PSTR 1032  // u16 stride: byte stride 2064 (16B aligned), dw 516 ≡ 4 mod 8 -> conflict-free b128
__global__ __launch_bounds__(256, 2) void attn_mfma_kernel(
    const u16* __restrict__ Qh, const u16* __restrict__ Kh,
    const u16* __restrict__ VT, const float* __restrict__ gamma_p,
    u16* __restrict__ attn_out)
{
    __shared__ __align__(16) u16 P[32 * PSTR];
    __shared__ float wred[4][32][4];
    __shared__ float dred[4][32];
    __shared__ float aArr[32], cmArr[32], dinvArr[32];

    const int qt = blockIdx.x, bh = blockIdx.y;
    const int b = bh / HH, h = bh - b * HH;
    const int tid = threadIdx.x, wave = tid >> 6, lane = tid & 63;
    const int g = lane >> 4, fm = lane & 15;
    const float gamma = gamma_p[0];
    const int m0 = qt * 32;
    const u16* Qp = Qh + (size_t)bh * TT * HD;
    const u16* Kp = Kh + (size_t)bh * TT * HD;
    const u16* Vp = VT + (size_t)bh * HD * TT;

    bf16x8 af[2][2];
    #pragma unroll
    for (int mi = 0; mi < 2; mi++)
        #pragma unroll
        for (int ks = 0; ks < 2; ks++)
            af[mi][ks] = *reinterpret_cast<const bf16x8*>(
                Qp + (size_t)(m0 + mi * 16 + fm) * HD + ks * 32 + g * 8);

    const int n0w = wave * 256;
    f32x4 acc[16][2] = {};
    #pragma unroll
    for (int nj = 0; nj < 16; nj++) {
        const u16* kp = Kp + (size_t)(n0w + nj * 16 + fm) * HD + g * 8;
        bf16x8 b0 = *reinterpret_cast<const bf16x8*>(kp);
        bf16x8 b1 = *reinterpret_cast<const bf16x8*>(kp + 32);
        acc[nj][0] = MFMA16(af[0][0], b0, acc[nj][0]);
        acc[nj][0] = MFMA16(af[0][1], b1, acc[nj][0]);
        acc[nj][1] = MFMA16(af[1][0], b0, acc[nj][1]);
        acc[nj][1] = MFMA16(af[1][1], b1, acc[nj][1]);
    }

    #pragma unroll
    for (int mi = 0; mi < 2; mi++) {
        #pragma unroll
        for (int r = 0; r < 4; r++) {
            float s1 = 0.f, s2 = 0.f, mx = -3.4e38f, mn = 3.4e38f;
            #pragma unroll
            for (int nj = 0; nj < 16; nj++) {
                float v = acc[nj][mi][r];
                s1 += v; s2 = fmaf(v, v, s2);
                mx = fmaxf(mx, v); mn = fminf(mn, v);
            }
            #pragma unroll
            for (int msk = 1; msk < 16; msk <<= 1) {
                s1 += __shfl_xor(s1, msk);
                s2 += __shfl_xor(s2, msk);
                mx = fmaxf(mx, __shfl_xor(mx, msk));
                mn = fminf(mn, __shfl_xor(mn, msk));
            }
            if (fm == 0) {
                int row = mi * 16 + g * 4 + r;
                wred[wave][row][0] = s1; wred[wave][row][1] = s2;
                wred[wave][row][2] = mx; wred[wave][row][3] = mn;
            }
        }
    }
    __syncthreads();
    if (tid < 32) {
        float s1 = 0.f, s2 = 0.f, mx = -3.4e38f, mn = 3.4e38f;
        #pragma unroll
        for (int w = 0; w < 4; w++) {
            s1 += wred[w][tid][0]; s2 += wred[w][tid][1];
            mx = fmaxf(mx, wred[w][tid][2]); mn = fminf(mn, wred[w][tid][3]);
        }
        float var = (s2 - s1 * s1 * (1.f / TT)) * (1.f / (TT - 1));
        var = fmaxf(var, 0.f);
        float a = gamma / (sqrtf(var) + 8e-5f);
        aArr[tid] = a;
        cmArr[tid] = (a >= 0.f) ? a * mx : a * mn;
    }
    __syncthreads();

    #pragma unroll
    for (int mi = 0; mi < 2; mi++) {
        #pragma unroll
        for (int r = 0; r < 4; r++) {
            const int row = mi * 16 + g * 4 + r;
            const float a = aArr[row], cm = cmArr[row];
            float dp = 0.f;
            #pragma unroll
            for (int nj = 0; nj < 16; nj++) {
                float p = __expf(fmaf(a, acc[nj][mi][r], -cm));
                u16 pb = f2us(p);
                dp += us2f(pb);
                P[row * PSTR + n0w + nj * 16 + fm] = pb;
            }
            #pragma unroll
            for (int msk = 1; msk < 16; msk <<= 1) dp += __shfl_xor(dp, msk);
            if (fm == 0) dred[wave][row] = dp;
        }
    }
    __syncthreads();
    if (tid < 32)
        dinvArr[tid] = 1.f / (dred[0][tid] + dred[1][tid] + dred[2][tid] + dred[3][tid]);
    __syncthreads();

    f32x4 oacc[2] = {};
    #pragma unroll 4
    for (int ks = 0; ks < 32; ks++) {
        bf16x8 bv = *reinterpret_cast<const bf16x8*>(
            Vp + (size_t)(wave * 16 + fm) * TT + ks * 32 + g * 8);
        bf16x8 a0 = *reinterpret_cast<const bf16x8*>(&P[(size_t)fm * PSTR + ks * 32 + g * 8]);
        bf16x8 a1 = *reinterpret_cast<const bf16x8*>(&P[(size_t)(16 + fm) * PSTR + ks * 32 + g * 8]);
        oacc[0] = MFMA16(a0, bv, oacc[0]);
        oacc[1] = MFMA16(a1, bv, oacc[1]);
    }
    #pragma unroll
    for (int mi = 0; mi < 2; mi++) {
        #pragma unroll
        for (int r = 0; r < 4; r++) {
            int row = mi * 16 + g * 4 + r;
            int t = m0 + row;
            attn_out[((size_t)(b * TT + t)) * DD + h * HD + wave * 16 + fm] =
                f2us(oacc[mi][r] * dinvArr[row]);
        }
    }
}

// ---------------------------------------------------------------------------
// LayerNorm over D=768 (LN1): in1 -> outF fp32 + outH bf16.
// ---------------------------------------------------------------------------
__global__ __launch_bounds__(256) void ln_kernel(
    const float* __restrict__ in1,
    const float* __restrict__ g, const float* __restrict__ bta,
    float* __restrict__ outF, u16* __restrict__ outH)
{
    const int row = blockIdx.x, tid = threadIdx.x;
    __shared__ float red[256];
    const size_t base = (size_t)row * DD;
    float v[3];
    #pragma unroll
    for (int i = 0; i < 3; i++) v[i] = in1[base + tid + i * 256];
    float s = v[0] + v[1] + v[2];
    red[tid] = s; __syncthreads();
    #pragma unroll
    for (int o = 128; o > 0; o >>= 1) { if (tid < o) red[tid] += red[tid + o]; __syncthreads(); }
    const float mean = red[0] * (1.f / 768.f);
    __syncthreads();
    float qv = 0.f;
    #pragma unroll
    for (int i = 0; i < 3; i++) { float d = v[i] - mean; qv += d * d; }
    red[tid] = qv; __syncthreads();
    #pragma unroll
    for (int o = 128; o > 0; o >>= 1) { if (tid < o) red[tid] += red[tid + o]; __syncthreads(); }
    const float var = red[0] * (1.f / 768.f);
    const float rs = rsqrtf(var + 1e-5f);
    #pragma unroll
    for (int i = 0; i < 3; i++) {
        int c = tid + i * 256;
        float o = (v[i] - mean) * rs * g[c] + bta[c];
        outF[base + c] = o;
        outH[base + c] = f2us(o);
    }
}

// ---------------------------------------------------------------------------
// LN2: t = x + sum of 8 split-K partials + sum_e comb[m,e]*b2[e,c]; layernorm.
// p7 may alias outF (d_out): all reads precede the first barrier, rows are
// block-disjoint, so the late store is safe.
// ---------------------------------------------------------------------------
__global__ __launch_bounds__(256) void ln2_kernel(
    const float* __restrict__ x,
    const float* __restrict__ p0, const float* __restrict__ p1,
    const float* __restrict__ p2, const float* __restrict__ p3,
    const float* __restrict__ p4, const float* __restrict__ p5,
    const float* __restrict__ p6, const float* __restrict__ p7,
    const float* __restrict__ comb, const float* __restrict__ b2,
    const float* __restrict__ g, const float* __restrict__ bta,
    float* __restrict__ outF)
{
    const int row = blockIdx.x, tid = threadIdx.x;
    __shared__ float red[256];
    const size_t base = (size_t)row * DD;
    const float c0 = comb[row * NE + 0], c1 = comb[row * NE + 1];
    const float c2 = comb[row * NE + 2], c3 = comb[row * NE + 3];
    float v[3];
    #pragma unroll
    for (int i = 0; i < 3; i++) {
        int c = tid + i * 256;
        float t = x[base + c];
        t += p0[base + c] + p1[base + c] + p2[base + c] + p3[base + c];
        t += p4[base + c] + p5[base + c] + p6[base + c] + p7[base + c];
        t = fmaf(c0, b2[c], t);
        t = fmaf(c1, b2[DD + c], t);
        t = fmaf(c2, b2[2 * DD + c], t);
        t = fmaf(c3, b2[3 * DD + c], t);
        v[i] = t;
    }
    float s = v[0] + v[1] + v[2];
    red[tid] = s; __syncthreads();
    #pragma unroll
    for (int o = 128; o > 0; o >>= 1) { if (tid < o) red[tid] += red[tid + o]; __syncthreads(); }
    const float mean = red[0] * (1.f / 768.f);
    __syncthreads();
    float qv = 0.f;
    #pragma unroll
    for (int i = 0; i < 3; i++) { float d = v[i] - mean; qv += d * d; }
    red[tid] = qv; __syncthreads();
    #pragma unroll
    for (int o = 128; o > 0; o >>= 1) { if (tid < o) red[tid] += red[tid + o]; __syncthreads(); }
    const float var = red[0] * (1.f / 768.f);
    const float rs = rsqrtf(var + 1e-5f);
    #pragma unroll
    for (int i = 0; i < 3; i++) {
        int c = tid + i * 256;
        outF[base + c] = (v[i] - mean) * rs * g[c] + bta[c];
    }
}

// ---------------------------------------------------------------------------
// Gate: one wave per token. softmax over E=4, top-2 -> combine weights.
// ---------------------------------------------------------------------------
__global__ __launch_bounds__(256) void gate_kernel(
    const float* __restrict__ x, const float* __restrict__ Wg,
    const float* __restrict__ bg, float* __restrict__ comb)
{
    const int wid = threadIdx.x >> 6, lane = threadIdx.x & 63;
    const int t = blockIdx.x * 4 + wid;
    const float* xr = x + (size_t)t * DD;
    float g[NE];
    #pragma unroll
    for (int e = 0; e < NE; e++) {
        float p = 0.f;
        for (int d = lane; d < DD; d += 64) p += xr[d] * Wg[e * DD + d];
        #pragma unroll
        for (int off = 32; off > 0; off >>= 1) p += __shfl_down(p, off, 64);
        g[e] = p;
    }
    if (lane == 0) {
        float m = -1e30f;
        #pragma unroll
        for (int e = 0; e < NE; e++) { g[e] += bg[e]; m = fmaxf(m, g[e]); }
        float ex[NE], s = 0.f;
        #pragma unroll
        for (int e = 0; e < NE; e++) { ex[e] = __expf(g[e] - m); s += ex[e]; }
        #pragma unroll
        for (int e = 0; e < NE; e++) ex[e] /= s;
        int e1 = 0;
        #pragma unroll
        for (int e = 1; e < NE; e++) if (ex[e] > ex[e1]) e1 = e;
        int e2 = -1;
        #pragma unroll
        for (int e = 0; e < NE; e++) if (e != e1 && (e2 < 0 || ex[e] > ex[e2])) e2 = e;
        float c[NE] = {0.f, 0.f, 0.f, 0.f};
        c[e1] = ex[e1]; c[e2] = ex[e2];
        #pragma unroll
        for (int e = 0; e < NE; e++) comb[(size_t)t * NE + e] = c[e];
    }
}

extern "C" void kernel_launch(void* const* d_in, const int* in_sizes, int n_in,
                              void* d_out, int out_size, void* d_ws, size_t ws_size,
                              hipStream_t stream)
{
    const float* src  = (const float*)d_in[0];
    const float* Wq   = (const float*)d_in[2];  const float* bq = (const float*)d_in[3];
    const float* Wk   = (const float*)d_in[4];  const float* bk = (const float*)d_in[5];
    const float* Wv   = (const float*)d_in[6];  const float* bv = (const float*)d_in[7];
    const float* Wo   = (const float*)d_in[8];  const float* bo = (const float*)d_in[9];
    const float* gam  = (const float*)d_in[10];
    const float* ln1g = (const float*)d_in[11]; const float* ln1b = (const float*)d_in[12];
    const float* ln2g = (const float*)d_in[13]; const float* ln2b = (const float*)d_in[14];
    const float* Wg   = (const float*)d_in[15]; const float* bg = (const float*)d_in[16];
    const float* W1   = (const float*)d_in[17]; const float* b1 = (const float*)d_in[18];
    const float* W2   = (const float*)d_in[19]; const float* b2 = (const float*)d_in[20];
    (void)ws_size; (void)in_sizes; (void)n_in; (void)out_size;

    char* ws = (char*)d_ws;
    // persistent regions
    u16*   W1T  = (u16*)(ws);                              // 18,874,368 B (dead after FF1 -> partials 4..6)
    u16*   W2T  = (u16*)(ws + 18874368);                   // 18,874,368 B
    u16*   hb   = (u16*)(ws + 37748736);                   // 50,331,648 B
    float* x    = (float*)(ws + 88080384);                 //  6,291,456 B
    u16*   xh   = (u16*)(ws + 94371840);                   //  3,145,728 B
    float* ffp  = (float*)(ws + 97517568);                 // 25,165,824 B (partials 0..3)
    float* comb = (float*)(ws + 122683392);                //     32,768 B
    float* bqkv = (float*)(ws + 122716160);                //      9,216 B
    // aliases inside hb region (all dead before FF1 writes hb)
    char* H = ws + 37748736;
    u16*   Qh     = (u16*)(H);                             //  3,145,728 B
    u16*   Kh     = (u16*)(H + 3145728);                   //  3,145,728 B
    u16*   VTh    = (u16*)(H + 6291456);                   //  3,145,728 B
    u16*   src_h  = (u16*)(H + 9437184);                   //  3,145,728 B
    u16*   attn_h = (u16*)(H + 12582912);                  //  3,145,728 B
    u16*   WqkvH  = (u16*)(H + 15728640);                  //  3,538,944 B
    u16*   WoH    = (u16*)(H + 19267584);                  //  1,179,648 B
    float* r1     = (float*)(H + 20447232);                //  6,291,456 B
    // FF2 split-K partials 4..6 live in the (dead) W1T region; 7 in d_out.
    float* ffpB = (float*)ws;
    const long PZ = (long)NTOK * DD;

    const int DW = DD * DD;  // 589824

    // ---- weight/activation conversions ----
    convert_kernel<<<(NTOK * DD / 8 + 255) / 256, 256, 0, stream>>>(src, src_h, NTOK * DD / 8);
    convert_kernel<<<(DW / 8 + 255) / 256, 256, 0, stream>>>(Wq, WqkvH, DW / 8);
    convert_kernel<<<(DW / 8 + 255) / 256, 256, 0, stream>>>(Wk, WqkvH + DW, DW / 8);
    convert_kernel<<<(DW / 8 + 255) / 256, 256, 0, stream>>>(Wv, WqkvH + 2 * DW, DW / 8);
    convert_kernel<<<(DW / 8 + 255) / 256, 256, 0, stream>>>(Wo, WoH, DW / 8);
    hipMemcpyAsync(bqkv, bq, DD * 4, hipMemcpyDeviceToDevice, stream);
    hipMemcpyAsync(bqkv + DD, bk, DD * 4, hipMemcpyDeviceToDevice, stream);
    hipMemcpyAsync(bqkv + 2 * DD, bv, DD * 4, hipMemcpyDeviceToDevice, stream);
    for (int e = 0; e < NE; e++) {
        transpose_convert_kernel<<<dim3(FFD / 32, DD / 32), 256, 0, stream>>>(
            W1 + (size_t)e * DD * FFD, W1T + (size_t)e * FFD * DD, DD, FFD, DD);
        transpose_convert_kernel<<<dim3(DD / 32, FFD / 32), 256, 0, stream>>>(
            W2 + (size_t)e * FFD * DD, W2T + (size_t)e * FFD, FFD, DD, NE * FFD);
    }

    // ---- QKV (batched, N=2304) -> bf16 Q,K [B,H,T,64], V^T [B,H,64,T] ----
    gemm_bt_kernel<<<dim3(2304 / 128, NTOK / 128, 1), 256, 0, stream>>>(
        src_h, DD, 0, WqkvH, DD, 0, DD, 0, 0,
        nullptr, Qh, Kh, VTh, 0, 0, bqkv, 0, nullptr, nullptr);

    // ---- attention (MFMA) ----
    attn_mfma_kernel<<<dim3(TT / 32, BB * HH), 256, 0, stream>>>(
        Qh, Kh, VTh, gam, attn_h);

    // ---- Wo projection + residual ----
    gemm_bt_kernel<<<dim3(DD / 128, NTOK / 128, 1), 256, 0, stream>>>(
        attn_h, DD, 0, WoH, DD, 0, DD, 1, 0,
        r1, nullptr, nullptr, nullptr, DD, 0, bo, 0, src, nullptr);

    // ---- LN1 ----
    ln_kernel<<<NTOK, 256, 0, stream>>>(r1, ln1g, ln1b, x, xh);

    // ---- gate ----
    gate_kernel<<<NTOK / 4, 256, 0, stream>>>(x, Wg, bg, comb);

    // ---- FF1 (all experts, comb folded in; m-fastest grid for W1-tile reuse) ----
    gemm_bt_kernel<<<dim3(NTOK / 128, FFD / 128, NE), 256, 0, stream>>>(
        xh, DD, 0, W1T, DD, (long)FFD * DD, DD, 2, 1,
        nullptr, hb, nullptr, nullptr, NE * FFD, FFD, b1, FFD, nullptr, comb);

    // ---- FF2 as one merged-K GEMM (K=12288), split-K into 8 slices of 1536 ->
    //      8 fp32 partial slabs (ffp0-3, W1T-region 4-6, d_out as 7) ----
    gemm_bt_kernel<<<dim3(DD / 128, NTOK / 128, 8), 256, 0, stream>>>(
        hb, NE * FFD, 1536L, W2T, NE * FFD, 1536L, 1536, 3, 0,
        ffp, (u16*)ffpB, (u16*)d_out, nullptr, DD, PZ, nullptr, 0, nullptr, nullptr);

    // ---- LN2 (x + 8 partials + comb*b2, then layernorm) ----
    ln2_kernel<<<NTOK, 256, 0, stream>>>(
        x, ffp, ffp + PZ, ffp + 2 * PZ, ffp + 3 * PZ,
        ffpB, ffpB + PZ, ffpB + 2 * PZ, (float*)d_out,
        comb, b2, ln2g, ln2b, (float*)d_out);
}

// Round 7
// 489.334 us; speedup vs baseline: 3.9402x; 1.0448x over previous
//
#include <hip/hip_runtime.h>

typedef unsigned short u16;
typedef short bf16x8 __attribute__((ext_vector_type(8)));
typedef float f32x4 __attribute__((ext_vector_type(4)));

#define BB 2
#define TT 1024
#define DD 768
#define HH 12
#define HD 64
#define FFD 3072
#define NE 4
#define NTOK (BB*TT)

#define MFMA16(a, b, c) __builtin_amdgcn_mfma_f32_16x16x32_bf16((a), (b), (c), 0, 0, 0)

#define ASYNC16(gsrc, ldst)                                                    \
    __builtin_amdgcn_global_load_lds(                                          \
        (const __attribute__((address_space(1))) void*)(gsrc),                 \
        (__attribute__((address_space(3))) void*)(ldst), 16, 0, 0)

__device__ __forceinline__ float us2f(u16 u) {
    return __uint_as_float(((unsigned int)u) << 16);
}
__device__ __forceinline__ u16 f2us(float f) {
    unsigned int x = __float_as_uint(f);
    x += 0x7fffu + ((x >> 16) & 1u);
    return (u16)(x >> 16);
}

// ---------------------------------------------------------------------------
// Flat fp32 -> bf16 convert. n8 = n/8 work items.
// ---------------------------------------------------------------------------
__global__ __launch_bounds__(256) void convert_kernel(
    const float* __restrict__ in, u16* __restrict__ out, int n8)
{
    int i = blockIdx.x * 256 + threadIdx.x;
    if (i >= n8) return;
    const float4* p = reinterpret_cast<const float4*>(in) + (size_t)i * 2;
    float4 a = p[0], b = p[1];
    u16 o[8] = {f2us(a.x), f2us(a.y), f2us(a.z), f2us(a.w),
                f2us(b.x), f2us(b.y), f2us(b.z), f2us(b.w)};
    *reinterpret_cast<uint4*>(out + (size_t)i * 8) = *reinterpret_cast<uint4*>(o);
}

// ---------------------------------------------------------------------------
// Transpose + convert (vectorized): per z, src [.,C] fp32 -> dst bf16 with
// dst[c*dstStride + r]. float4 reads, uint2 (4xbf16) packed writes.
// ---------------------------------------------------------------------------
__global__ __launch_bounds__(256) void transpose_convert_kernel(
    const float* __restrict__ src, u16* __restrict__ dst,
    int C, int dstStride, long srcZ, long dstZ)
{
    __shared__ float tile[32][33];
    const float* s = src + (size_t)blockIdx.z * srcZ;
    u16* d = dst + (size_t)blockIdx.z * dstZ;
    const int c0 = blockIdx.x * 32, r0 = blockIdx.y * 32;
    const int tid = threadIdx.x;
    {
        const int r = tid >> 3, cs = (tid & 7) * 4;
        float4 v = *reinterpret_cast<const float4*>(&s[(size_t)(r0 + r) * C + c0 + cs]);
        tile[r][cs] = v.x; tile[r][cs + 1] = v.y;
        tile[r][cs + 2] = v.z; tile[r][cs + 3] = v.w;
    }
    __syncthreads();
    {
        const int c = tid >> 3, rs = (tid & 7) * 4;
        u16 o[4] = {f2us(tile[rs][c]), f2us(tile[rs + 1][c]),
                    f2us(tile[rs + 2][c]), f2us(tile[rs + 3][c])};
        *reinterpret_cast<uint2*>(&d[(size_t)(c0 + c) * dstStride + r0 + rs]) =
            *reinterpret_cast<uint2*>(o);
    }
}

// ---------------------------------------------------------------------------
// bf16 MFMA GEMM: C[M,N] = A[M,K] * Bt[N,K]^T  (both row-major, K-contiguous)
// 128x128 tile, 4 waves, 16x16x32 MFMA, fp32 accum.
// Staging: global_load_lds 16B into unpadded [128][32] u16 LDS; XOR column-
// group swizzle at the global-source side (bank-balanced, conflict-free).
// modes:
//  0 QKV:  y=acc+biasF[n]; bf16 scatter: Q,K -> [B,H,T,64]; V -> VT [B,H,64,T]
//  1 Wo-direct (unused)
//  2 FF1:  y=relu(acc+biasF[z*biasZ+n])*comb[m*4+z] -> bf16 outH[m*ldc+cZ*z+n]
//          via LDS-repacked dwordx4 stores
//  3 split-K partial store: z<4 -> outF+z*cZ; 4..6 -> (float*)outH+(z-4)*cZ;
//          z==7 -> (float*)outH2.  A/B z-offset via aZ/bZ (k-slice).
// mswap: if 1, blockIdx.x indexes M (m-fastest dispatch for B-tile L2 reuse).
// ---------------------------------------------------------------------------
__global__ __launch_bounds__(256) void gemm_bt_kernel(
    const u16* __restrict__ A, int lda, long aZ,
    const u16* __restrict__ Bt, int ldb, long bZ,
    int K, int mode, int mswap,
    float* __restrict__ outF, u16* __restrict__ outH,
    u16* __restrict__ outH2, u16* __restrict__ outH3,
    int ldc, long cZ,
    const float* __restrict__ biasF, int biasZ,
    const float* __restrict__ src, const float* __restrict__ comb)
{
    __shared__ __align__(16) u16 As[128 * 32];
    __shared__ __align__(16) u16 Bs[128 * 32];
    const int tid = threadIdx.x;
    const int z = blockIdx.z;
    const int bx = mswap ? blockIdx.y : blockIdx.x;
    const int by = mswap ? blockIdx.x : blockIdx.y;
    const int m0 = by * 128, n0 = bx * 128;
    const u16* Ab = A + (size_t)z * aZ;
    const u16* Bb = Bt + (size_t)z * bZ;

    const int wave = tid >> 6, lane = tid & 63;
    const int wm = (wave & 1) * 64, wn = (wave >> 1) * 64;
    const int fm = lane & 15;
    const int g  = lane >> 4;

    // staging: wave w covers tile rows [w*32, w*32+32), 2 instrs per operand
    const int lrow = lane >> 2;             // 0..15
    const int lgrp = lane & 3;              // 0..3
    const int cg   = (lgrp ^ ((lrow >> 1) & 3)) * 8;   // swizzled col group
    const int r0   = wave * 32 + lrow;
    const u16* aG0 = Ab + (size_t)(m0 + r0) * lda + cg;
    const u16* aG1 = Ab + (size_t)(m0 + r0 + 16) * lda + cg;
    const u16* bG0 = Bb + (size_t)(n0 + r0) * ldb + cg;
    const u16* bG1 = Bb + (size_t)(n0 + r0 + 16) * ldb + cg;
    u16* aL0 = &As[(wave * 32) * 32];
    u16* aL1 = &As[(wave * 32 + 16) * 32];
    u16* bL0 = &Bs[(wave * 32) * 32];
    u16* bL1 = &Bs[(wave * 32 + 16) * 32];

    // fragment LDS addresses (loop-invariant); read swizzle mirrors store
    const int sw8 = ((fm >> 1) & 3) * 8;
    const u16* pa[4]; const u16* pb[4];
    #pragma unroll
    for (int i = 0; i < 4; i++) {
        pa[i] = &As[(wm + i * 16 + fm) * 32 + ((g * 8) ^ sw8)];
        pb[i] = &Bs[(wn + i * 16 + fm) * 32 + ((g * 8) ^ sw8)];
    }

    f32x4 acc[4][4] = {};

    for (int k0 = 0; k0 < K; k0 += 32) {
        ASYNC16(aG0 + k0, aL0);
        ASYNC16(aG1 + k0, aL1);
        ASYNC16(bG0 + k0, bL0);
        ASYNC16(bG1 + k0, bL1);
        __syncthreads();

        bf16x8 af[4], bf[4];
        #pragma unroll
        for (int i = 0; i < 4; i++) af[i] = *reinterpret_cast<const bf16x8*>(pa[i]);
        #pragma unroll
        for (int j = 0; j < 4; j++) bf[j] = *reinterpret_cast<const bf16x8*>(pb[j]);
        #pragma unroll
        for (int i = 0; i < 4; i++)
            #pragma unroll
            for (int j = 0; j < 4; j++)
                acc[i][j] = MFMA16(af[i], bf[j], acc[i][j]);
        __syncthreads();
    }

    // C/D layout: col = lane&15, row = (lane>>4)*4 + reg   [m89-verified]
    const int cn = lane & 15, cr = (lane >> 4) * 4;

    if (mode == 2) {
        // LDS-repacked epilogue: 4 passes x 32 rows, dwordx4 coalesced stores
        u16* Cs = As;
        #pragma unroll
        for (int i = 0; i < 4; i++) {
            if (i) __syncthreads();
            #pragma unroll
            for (int j = 0; j < 4; j++) {
                const int n = n0 + wn + j * 16 + cn;
                const float bias = biasF[(size_t)z * biasZ + n];
                #pragma unroll
                for (int r = 0; r < 4; r++) {
                    const int m = m0 + wm + i * 16 + cr + r;
                    float y = fmaxf(acc[i][j][r] + bias, 0.f) * comb[m * NE + z];
                    Cs[((wave & 1) * 16 + cr + r) * 128 + wn + j * 16 + cn] = f2us(y);
                }
            }
            __syncthreads();
            const int lr2 = tid >> 3, c2 = (tid & 7) * 16;
            const int m2 = m0 + (lr2 >> 4) * 64 + i * 16 + (lr2 & 15);
            u16* dst = outH + (size_t)m2 * ldc + (size_t)z * cZ + n0 + c2;
            *reinterpret_cast<uint4*>(dst) =
                *reinterpret_cast<const uint4*>(&Cs[lr2 * 128 + c2]);
            *reinterpret_cast<uint4*>(dst + 8) =
                *reinterpret_cast<const uint4*>(&Cs[lr2 * 128 + c2 + 8]);
        }
        return;
    }

    #pragma unroll
    for (int i = 0; i < 4; i++) {
        #pragma unroll
        for (int j = 0; j < 4; j++) {
            const int n = n0 + wn + j * 16 + cn;
            #pragma unroll
            for (int r = 0; r < 4; r++) {
                const int m = m0 + wm + i * 16 + cr + r;
                float y = acc[i][j][r];
                if (mode == 0) {
                    y += biasF[n];
                    int which = (n >= 1536) ? 2 : (n >= 768 ? 1 : 0);
                    int nn = n - which * 768;
                    int bb = m >> 10, t = m & 1023;
                    int hh = nn >> 6, d = nn & 63;
                    if (which == 0)
                        outH[(((size_t)(bb * HH + hh) * TT + t) << 6) + d] = f2us(y);
                    else if (which == 1)
                        outH2[(((size_t)(bb * HH + hh) * TT + t) << 6) + d] = f2us(y);
                    else
                        outH3[(((size_t)(bb * HH + hh) * HD + d) << 10) + t] = f2us(y);
                } else if (mode == 1) {
                    size_t idx = (size_t)m * ldc + n;
                    outF[idx] = y + biasF[n] + src[idx];
                } else {
                    float* base = (z < 4) ? (outF + (size_t)z * cZ)
                                : (z < 7) ? ((float*)outH + (size_t)(z - 4) * cZ)
                                          : (float*)outH2;
                    base[(size_t)m * ldc + n] = y;
                }
            }
        }
    }
}

// ---------------------------------------------------------------------------
// MFMA attention. Block = (qt 32 rows, b*12+h). 4 waves.
// Phase 1: S[32][1024] in accumulators (wave w covers cols w*256..+256).
// zscore is scale-invariant: a = gamma/(std_ddof1(S)+EPS_Z/0.125); shift
// cancels in softmax; cm = max(a*S) for stability.
// Phase 2: P bf16 in LDS; O = P*V via MFMA (V pre-transposed [B,H,64,T]).
// ---------------------------------------------------------------------------
#define PSTR 1032  // u16 stride: byte stride 2064 (16B aligned), dw 516 ≡ 4 mod 8 -> conflict-free b128
__global__ __launch_bounds__(256, 2) void attn_mfma_kernel(
    const u16* __restrict__ Qh, const u16* __restrict__ Kh,
    const u16* __restrict__ VT, const float* __restrict__ gamma_p,
    u16* __restrict__ attn_out)
{
    __shared__ __align__(16) u16 P[32 * PSTR];
    __shared__ float wred[4][32][4];
    __shared__ float dred[4][32];
    __shared__ float aArr[32], cmArr[32], dinvArr[32];

    const int qt = blockIdx.x, bh = blockIdx.y;
    const int b = bh / HH, h = bh - b * HH;
    const int tid = threadIdx.x, wave = tid >> 6, lane = tid & 63;
    const int g = lane >> 4, fm = lane & 15;
    const float gamma = gamma_p[0];
    const int m0 = qt * 32;
    const u16* Qp = Qh + (size_t)bh * TT * HD;
    const u16* Kp = Kh + (size_t)bh * TT * HD;
    const u16* Vp = VT + (size_t)bh * HD * TT;

    bf16x8 af[2][2];
    #pragma unroll
    for (int mi = 0; mi < 2; mi++)
        #pragma unroll
        for (int ks = 0; ks < 2; ks++)
            af[mi][ks] = *reinterpret_cast<const bf16x8*>(
                Qp + (size_t)(m0 + mi * 16 + fm) * HD + ks * 32 + g * 8);

    const int n0w = wave * 256;
    f32x4 acc[16][2] = {};
    #pragma unroll
    for (int nj = 0; nj < 16; nj++) {
        const u16* kp = Kp + (size_t)(n0w + nj * 16 + fm) * HD + g * 8;
        bf16x8 b0 = *reinterpret_cast<const bf16x8*>(kp);
        bf16x8 b1 = *reinterpret_cast<const bf16x8*>(kp + 32);
        acc[nj][0] = MFMA16(af[0][0], b0, acc[nj][0]);
        acc[nj][0] = MFMA16(af[0][1], b1, acc[nj][0]);
        acc[nj][1] = MFMA16(af[1][0], b0, acc[nj][1]);
        acc[nj][1] = MFMA16(af[1][1], b1, acc[nj][1]);
    }

    #pragma unroll
    for (int mi = 0; mi < 2; mi++) {
        #pragma unroll
        for (int r = 0; r < 4; r++) {
            float s1 = 0.f, s2 = 0.f, mx = -3.4e38f, mn = 3.4e38f;
            #pragma unroll
            for (int nj = 0; nj < 16; nj++) {
                float v = acc[nj][mi][r];
                s1 += v; s2 = fmaf(v, v, s2);
                mx = fmaxf(mx, v); mn = fminf(mn, v);
            }
            #pragma unroll
            for (int msk = 1; msk < 16; msk <<= 1) {
                s1 += __shfl_xor(s1, msk);
                s2 += __shfl_xor(s2, msk);
                mx = fmaxf(mx, __shfl_xor(mx, msk));
                mn = fminf(mn, __shfl_xor(mn, msk));
            }
            if (fm == 0) {
                int row = mi * 16 + g * 4 + r;
                wred[wave][row][0] = s1; wred[wave][row][1] = s2;
                wred[wave][row][2] = mx; wred[wave][row][3] = mn;
            }
        }
    }
    __syncthreads();
    if (tid < 32) {
        float s1 = 0.f, s2 = 0.f, mx = -3.4e38f, mn = 3.4e38f;
        #pragma unroll
        for (int w = 0; w < 4; w++) {
            s1 += wred[w][tid][0]; s2 += wred[w][tid][1];
            mx = fmaxf(mx, wred[w][tid][2]); mn = fminf(mn, wred[w][tid][3]);
        }
        float var = (s2 - s1 * s1 * (1.f / TT)) * (1.f / (TT - 1));
        var = fmaxf(var, 0.f);
        float a = gamma / (sqrtf(var) + 8e-5f);
        aArr[tid] = a;
        cmArr[tid] = (a >= 0.f) ? a * mx : a * mn;
    }
    __syncthreads();

    #pragma unroll
    for (int mi = 0; mi < 2; mi++) {
        #pragma unroll
        for (int r = 0; r < 4; r++) {
            const int row = mi * 16 + g * 4 + r;
            const float a = aArr[row], cm = cmArr[row];
            float dp = 0.f;
            #pragma unroll
            for (int nj = 0; nj < 16; nj++) {
                float p = __expf(fmaf(a, acc[nj][mi][r], -cm));
                u16 pb = f2us(p);
                dp += us2f(pb);
                P[row * PSTR + n0w + nj * 16 + fm] = pb;
            }
            #pragma unroll
            for (int msk = 1; msk < 16; msk <<= 1) dp += __shfl_xor(dp, msk);
            if (fm == 0) dred[wave][row] = dp;
        }
    }
    __syncthreads();
    if (tid < 32)
        dinvArr[tid] = 1.f / (dred[0][tid] + dred[1][tid] + dred[2][tid] + dred[3][tid]);
    __syncthreads();

    f32x4 oacc[2] = {};
    #pragma unroll 4
    for (int ks = 0; ks < 32; ks++) {
        bf16x8 bv = *reinterpret_cast<const bf16x8*>(
            Vp + (size_t)(wave * 16 + fm) * TT + ks * 32 + g * 8);
        bf16x8 a0 = *reinterpret_cast<const bf16x8*>(&P[(size_t)fm * PSTR + ks * 32 + g * 8]);
        bf16x8 a1 = *reinterpret_cast<const bf16x8*>(&P[(size_t)(16 + fm) * PSTR + ks * 32 + g * 8]);
        oacc[0] = MFMA16(a0, bv, oacc[0]);
        oacc[1] = MFMA16(a1, bv, oacc[1]);
    }
    #pragma unroll
    for (int mi = 0; mi < 2; mi++) {
        #pragma unroll
        for (int r = 0; r < 4; r++) {
            int row = mi * 16 + g * 4 + r;
            int t = m0 + row;
            attn_out[((size_t)(b * TT + t)) * DD + h * HD + wave * 16 + fm] =
                f2us(oacc[mi][r] * dinvArr[row]);
        }
    }
}

// ---------------------------------------------------------------------------
// LN1 fused: r1 = p0+p1+p2+p3 (Wo split-K partials) + src + bo; layernorm ->
// x fp32 + xh bf16.
// ---------------------------------------------------------------------------
__global__ __launch_bounds__(256) void ln1_kernel(
    const float* __restrict__ p0, const float* __restrict__ p1,
    const float* __restrict__ p2, const float* __restrict__ p3,
    const float* __restrict__ src, const float* __restrict__ bo,
    const float* __restrict__ g, const float* __restrict__ bta,
    float* __restrict__ outF, u16* __restrict__ outH)
{
    const int row = blockIdx.x, tid = threadIdx.x;
    __shared__ float red[256];
    const size_t base = (size_t)row * DD;
    float v[3];
    #pragma unroll
    for (int i = 0; i < 3; i++) {
        int c = tid + i * 256;
        v[i] = p0[base + c] + p1[base + c] + p2[base + c] + p3[base + c]
             + src[base + c] + bo[c];
    }
    float s = v[0] + v[1] + v[2];
    red[tid] = s; __syncthreads();
    #pragma unroll
    for (int o = 128; o > 0; o >>= 1) { if (tid < o) red[tid] += red[tid + o]; __syncthreads(); }
    const float mean = red[0] * (1.f / 768.f);
    __syncthreads();
    float qv = 0.f;
    #pragma unroll
    for (int i = 0; i < 3; i++) { float d = v[i] - mean; qv += d * d; }
    red[tid] = qv; __syncthreads();
    #pragma unroll
    for (int o = 128; o > 0; o >>= 1) { if (tid < o) red[tid] += red[tid + o]; __syncthreads(); }
    const float var = red[0] * (1.f / 768.f);
    const float rs = rsqrtf(var + 1e-5f);
    #pragma unroll
    for (int i = 0; i < 3; i++) {
        int c = tid + i * 256;
        float o = (v[i] - mean) * rs * g[c] + bta[c];
        outF[base + c] = o;
        outH[base + c] = f2us(o);
    }
}

// ---------------------------------------------------------------------------
// LN2: t = x + sum of 8 split-K partials + sum_e comb[m,e]*b2[e,c]; layernorm.
// p7 may alias outF (d_out): all reads precede the first barrier, rows are
// block-disjoint, so the late store is safe.
// ---------------------------------------------------------------------------
__global__ __launch_bounds__(256) void ln2_kernel(
    const float* __restrict__ x,
    const float* __restrict__ p0, const float* __restrict__ p1,
    const float* __restrict__ p2, const float* __restrict__ p3,
    const float* __restrict__ p4, const float* __restrict__ p5,
    const float* __restrict__ p6, const float* __restrict__ p7,
    const float* __restrict__ comb, const float* __restrict__ b2,
    const float* __restrict__ g, const float* __restrict__ bta,
    float* __restrict__ outF)
{
    const int row = blockIdx.x, tid = threadIdx.x;
    __shared__ float red[256];
    const size_t base = (size_t)row * DD;
    const float c0 = comb[row * NE + 0], c1 = comb[row * NE + 1];
    const float c2 = comb[row * NE + 2], c3 = comb[row * NE + 3];
    float v[3];
    #pragma unroll
    for (int i = 0; i < 3; i++) {
        int c = tid + i * 256;
        float t = x[base + c];
        t += p0[base + c] + p1[base + c] + p2[base + c] + p3[base + c];
        t += p4[base + c] + p5[base + c] + p6[base + c] + p7[base + c];
        t = fmaf(c0, b2[c], t);
        t = fmaf(c1, b2[DD + c], t);
        t = fmaf(c2, b2[2 * DD + c], t);
        t = fmaf(c3, b2[3 * DD + c], t);
        v[i] = t;
    }
    float s = v[0] + v[1] + v[2];
    red[tid] = s; __syncthreads();
    #pragma unroll
    for (int o = 128; o > 0; o >>= 1) { if (tid < o) red[tid] += red[tid + o]; __syncthreads(); }
    const float mean = red[0] * (1.f / 768.f);
    __syncthreads();
    float qv = 0.f;
    #pragma unroll
    for (int i = 0; i < 3; i++) { float d = v[i] - mean; qv += d * d; }
    red[tid] = qv; __syncthreads();
    #pragma unroll
    for (int o = 128; o > 0; o >>= 1) { if (tid < o) red[tid] += red[tid + o]; __syncthreads(); }
    const float var = red[0] * (1.f / 768.f);
    const float rs = rsqrtf(var + 1e-5f);
    #pragma unroll
    for (int i = 0; i < 3; i++) {
        int c = tid + i * 256;
        outF[base + c] = (v[i] - mean) * rs * g[c] + bta[c];
    }
}

// ---------------------------------------------------------------------------
// Gate: one wave per token. softmax over E=4, top-2 -> combine weights.
// ---------------------------------------------------------------------------
__global__ __launch_bounds__(256) void gate_kernel(
    const float* __restrict__ x, const float* __restrict__ Wg,
    const float* __restrict__ bg, float* __restrict__ comb)
{
    const int wid = threadIdx.x >> 6, lane = threadIdx.x & 63;
    const int t = blockIdx.x * 4 + wid;
    const float* xr = x + (size_t)t * DD;
    float g[NE];
    #pragma unroll
    for (int e = 0; e < NE; e++) {
        float p = 0.f;
        for (int d = lane; d < DD; d += 64) p += xr[d] * Wg[e * DD + d];
        #pragma unroll
        for (int off = 32; off > 0; off >>= 1) p += __shfl_down(p, off, 64);
        g[e] = p;
    }
    if (lane == 0) {
        float m = -1e30f;
        #pragma unroll
        for (int e = 0; e < NE; e++) { g[e] += bg[e]; m = fmaxf(m, g[e]); }
        float ex[NE], s = 0.f;
        #pragma unroll
        for (int e = 0; e < NE; e++) { ex[e] = __expf(g[e] - m); s += ex[e]; }
        #pragma unroll
        for (int e = 0; e < NE; e++) ex[e] /= s;
        int e1 = 0;
        #pragma unroll
        for (int e = 1; e < NE; e++) if (ex[e] > ex[e1]) e1 = e;
        int e2 = -1;
        #pragma unroll
        for (int e = 0; e < NE; e++) if (e != e1 && (e2 < 0 || ex[e] > ex[e2])) e2 = e;
        float c[NE] = {0.f, 0.f, 0.f, 0.f};
        c[e1] = ex[e1]; c[e2] = ex[e2];
        #pragma unroll
        for (int e = 0; e < NE; e++) comb[(size_t)t * NE + e] = c[e];
    }
}

extern "C" void kernel_launch(void* const* d_in, const int* in_sizes, int n_in,
                              void* d_out, int out_size, void* d_ws, size_t ws_size,
                              hipStream_t stream)
{
    const float* src  = (const float*)d_in[0];
    const float* Wq   = (const float*)d_in[2];  const float* bq = (const float*)d_in[3];
    const float* Wk   = (const float*)d_in[4];  const float* bk = (const float*)d_in[5];
    const float* Wv   = (const float*)d_in[6];  const float* bv = (const float*)d_in[7];
    const float* Wo   = (const float*)d_in[8];  const float* bo = (const float*)d_in[9];
    const float* gam  = (const float*)d_in[10];
    const float* ln1g = (const float*)d_in[11]; const float* ln1b = (const float*)d_in[12];
    const float* ln2g = (const float*)d_in[13]; const float* ln2b = (const float*)d_in[14];
    const float* Wg   = (const float*)d_in[15]; const float* bg = (const float*)d_in[16];
    const float* W1   = (const float*)d_in[17]; const float* b1 = (const float*)d_in[18];
    const float* W2   = (const float*)d_in[19]; const float* b2 = (const float*)d_in[20];
    (void)ws_size; (void)in_sizes; (void)n_in; (void)out_size;

    char* ws = (char*)d_ws;
    // persistent regions
    u16*   W1T  = (u16*)(ws);                              // 18,874,368 B (dead after FF1 -> FF2 partials 4..6)
    u16*   W2T  = (u16*)(ws + 18874368);                   // 18,874,368 B
    u16*   hb   = (u16*)(ws + 37748736);                   // 50,331,648 B
    float* x    = (float*)(ws + 88080384);                 //  6,291,456 B
    u16*   xh   = (u16*)(ws + 94371840);                   //  3,145,728 B
    float* ffp  = (float*)(ws + 97517568);                 // 25,165,824 B (Wo partials, then FF2 partials 0..3)
    float* comb = (float*)(ws + 122683392);                //     32,768 B
    float* bqkv = (float*)(ws + 122716160);                //      9,216 B
    // aliases inside hb region (all dead before FF1 writes hb)
    char* H = ws + 37748736;
    u16*   Qh     = (u16*)(H);                             //  3,145,728 B
    u16*   Kh     = (u16*)(H + 3145728);                   //  3,145,728 B
    u16*   VTh    = (u16*)(H + 6291456);                   //  3,145,728 B
    u16*   src_h  = (u16*)(H + 9437184);                   //  3,145,728 B
    u16*   attn_h = (u16*)(H + 12582912);                  //  3,145,728 B
    u16*   WqkvH  = (u16*)(H + 15728640);                  //  3,538,944 B
    u16*   WoH    = (u16*)(H + 19267584);                  //  1,179,648 B
    // FF2 split-K partials 4..6 live in the (dead) W1T region; 7 in d_out.
    float* ffpB = (float*)ws;
    const long PZ = (long)NTOK * DD;

    const int DW = DD * DD;  // 589824

    // ---- weight/activation conversions ----
    convert_kernel<<<(NTOK * DD / 8 + 255) / 256, 256, 0, stream>>>(src, src_h, NTOK * DD / 8);
    convert_kernel<<<(DW / 8 + 255) / 256, 256, 0, stream>>>(Wq, WqkvH, DW / 8);
    convert_kernel<<<(DW / 8 + 255) / 256, 256, 0, stream>>>(Wk, WqkvH + DW, DW / 8);
    convert_kernel<<<(DW / 8 + 255) / 256, 256, 0, stream>>>(Wv, WqkvH + 2 * DW, DW / 8);
    convert_kernel<<<(DW / 8 + 255) / 256, 256, 0, stream>>>(Wo, WoH, DW / 8);
    hipMemcpyAsync(bqkv, bq, DD * 4, hipMemcpyDeviceToDevice, stream);
    hipMemcpyAsync(bqkv + DD, bk, DD * 4, hipMemcpyDeviceToDevice, stream);
    hipMemcpyAsync(bqkv + 2 * DD, bv, DD * 4, hipMemcpyDeviceToDevice, stream);
    // W1[e]: [768,3072] -> [3072,768] per expert
    transpose_convert_kernel<<<dim3(FFD / 32, DD / 32, NE), 256, 0, stream>>>(
        W1, W1T, FFD, DD, (long)DD * FFD, (long)FFD * DD);
    // W2[e]: [3072,768] -> W2T[n][e*3072+k], row stride 12288
    transpose_convert_kernel<<<dim3(DD / 32, FFD / 32, NE), 256, 0, stream>>>(
        W2, W2T, DD, NE * FFD, (long)FFD * DD, (long)FFD);

    // ---- QKV (batched, N=2304) -> bf16 Q,K [B,H,T,64], V^T [B,H,64,T] ----
    gemm_bt_kernel<<<dim3(2304 / 128, NTOK / 128, 1), 256, 0, stream>>>(
        src_h, DD, 0, WqkvH, DD, 0, DD, 0, 0,
        nullptr, Qh, Kh, VTh, 0, 0, bqkv, 0, nullptr, nullptr);

    // ---- attention (MFMA) ----
    attn_mfma_kernel<<<dim3(TT / 32, BB * HH), 256, 0, stream>>>(
        Qh, Kh, VTh, gam, attn_h);

    // ---- Wo projection split-K x4 -> fp32 partials in ffp ----
    gemm_bt_kernel<<<dim3(DD / 128, NTOK / 128, 4), 256, 0, stream>>>(
        attn_h, DD, 192L, WoH, DD, 192L, 192, 3, 0,
        ffp, nullptr, nullptr, nullptr, DD, PZ, nullptr, 0, nullptr, nullptr);

    // ---- LN1 (sums Wo partials + residual + bias inline) ----
    ln1_kernel<<<NTOK, 256, 0, stream>>>(
        ffp, ffp + PZ, ffp + 2 * PZ, ffp + 3 * PZ, src, bo,
        ln1g, ln1b, x, xh);

    // ---- gate ----
    gate_kernel<<<NTOK / 4, 256, 0, stream>>>(x, Wg, bg, comb);

    // ---- FF1 (all experts, comb folded in; m-fastest grid for W1-tile reuse) ----
    gemm_bt_kernel<<<dim3(NTOK / 128, FFD / 128, NE), 256, 0, stream>>>(
        xh, DD, 0, W1T, DD, (long)FFD * DD, DD, 2, 1,
        nullptr, hb, nullptr, nullptr, NE * FFD, FFD, b1, FFD, nullptr, comb);

    // ---- FF2 as one merged-K GEMM (K=12288), split-K into 8 slices of 1536 ->
    //      8 fp32 partial slabs (ffp0-3, W1T-region 4-6, d_out as 7) ----
    gemm_bt_kernel<<<dim3(DD / 128, NTOK / 128, 8), 256, 0, stream>>>(
        hb, NE * FFD, 1536L, W2T, NE * FFD, 1536L, 1536, 3, 0,
        ffp, (u16*)ffpB, (u16*)d_out, nullptr, DD, PZ, nullptr, 0, nullptr, nullptr);

    // ---- LN2 (x + 8 partials + comb*b2, then layernorm) ----
    ln2_kernel<<<NTOK, 256, 0, stream>>>(
        x, ffp, ffp + PZ, ffp + 2 * PZ, ffp + 3 * PZ,
        ffpB, ffpB + PZ, ffpB + 2 * PZ, (float*)d_out,
        comb, b2, ln2g, ln2b, (float*)d_out);
}

// Round 8
// 466.233 us; speedup vs baseline: 4.1355x; 1.0495x over previous
//
#include <hip/hip_runtime.h>

typedef unsigned short u16;
typedef short bf16x8 __attribute__((ext_vector_type(8)));
typedef float f32x4 __attribute__((ext_vector_type(4)));

#define BB 2
#define TT 1024
#define DD 768
#define HH 12
#define HD 64
#define FFD 3072
#define NE 4
#define NTOK (BB*TT)

#define MFMA16(a, b, c) __builtin_amdgcn_mfma_f32_16x16x32_bf16((a), (b), (c), 0, 0, 0)

#define ASYNC16(gsrc, ldst)                                                    \
    __builtin_amdgcn_global_load_lds(                                          \
        (const __attribute__((address_space(1))) void*)(gsrc),                 \
        (__attribute__((address_space(3))) void*)(ldst), 16, 0, 0)

__device__ __forceinline__ float us2f(u16 u) {
    return __uint_as_float(((unsigned int)u) << 16);
}
__device__ __forceinline__ u16 f2us(float f) {
    unsigned int x = __float_as_uint(f);
    x += 0x7fffu + ((x >> 16) & 1u);
    return (u16)(x >> 16);
}

// ---------------------------------------------------------------------------
// Flat fp32 -> bf16 convert. n8 = n/8 work items.
// ---------------------------------------------------------------------------
__global__ __launch_bounds__(256) void convert_kernel(
    const float* __restrict__ in, u16* __restrict__ out, int n8)
{
    int i = blockIdx.x * 256 + threadIdx.x;
    if (i >= n8) return;
    const float4* p = reinterpret_cast<const float4*>(in) + (size_t)i * 2;
    float4 a = p[0], b = p[1];
    u16 o[8] = {f2us(a.x), f2us(a.y), f2us(a.z), f2us(a.w),
                f2us(b.x), f2us(b.y), f2us(b.z), f2us(b.w)};
    *reinterpret_cast<uint4*>(out + (size_t)i * 8) = *reinterpret_cast<uint4*>(o);
}

// ---------------------------------------------------------------------------
// Transpose + convert (vectorized): per z, src [.,C] fp32 -> dst bf16 with
// dst[c*dstStride + r]. float4 reads, uint2 (4xbf16) packed writes.
// ---------------------------------------------------------------------------
__global__ __launch_bounds__(256) void transpose_convert_kernel(
    const float* __restrict__ src, u16* __restrict__ dst,
    int C, int dstStride, long srcZ, long dstZ)
{
    __shared__ float tile[32][33];
    const float* s = src + (size_t)blockIdx.z * srcZ;
    u16* d = dst + (size_t)blockIdx.z * dstZ;
    const int c0 = blockIdx.x * 32, r0 = blockIdx.y * 32;
    const int tid = threadIdx.x;
    {
        const int r = tid >> 3, cs = (tid & 7) * 4;
        float4 v = *reinterpret_cast<const float4*>(&s[(size_t)(r0 + r) * C + c0 + cs]);
        tile[r][cs] = v.x; tile[r][cs + 1] = v.y;
        tile[r][cs + 2] = v.z; tile[r][cs + 3] = v.w;
    }
    __syncthreads();
    {
        const int c = tid >> 3, rs = (tid & 7) * 4;
        u16 o[4] = {f2us(tile[rs][c]), f2us(tile[rs + 1][c]),
                    f2us(tile[rs + 2][c]), f2us(tile[rs + 3][c])};
        *reinterpret_cast<uint2*>(&d[(size_t)(c0 + c) * dstStride + r0 + rs]) =
            *reinterpret_cast<uint2*>(o);
    }
}

// ---------------------------------------------------------------------------
// bf16 MFMA GEMM: C[M,N] = A[M,K] * Bt[N,K]^T  (both row-major, K-contiguous)
// 128x128 tile, 4 waves, 16x16x32 MFMA, fp32 accum.
// Staging: global_load_lds 16B into unpadded [128][32] u16 LDS; XOR column-
// group swizzle at the global-source side (bank-balanced, conflict-free).
// modes:
//  0 QKV:  y=acc+biasF[n]; bf16 scatter: Q,K -> [B,H,T,64]; V -> VT [B,H,64,T]
//  2 FF1:  y=relu(acc+biasF[z*biasZ+n])*comb[m*4+z] -> bf16 outH[m*ldc+cZ*z+n]
//          via LDS-repacked dwordx4 stores
//  3 split-K partial store: z<4 -> outF+z*cZ; 4..6 -> (float*)outH+(z-4)*cZ;
//          z==7 -> (float*)outH2.  A/B z-offset via aZ/bZ (k-slice).
// swz (XCD-aware flat-grid decode; fid%8 assumed = XCD):
//  0: 3D grid as-is (bx=x, by=y, z=z)
//  1: FF1 flat 1536: xcd=fid&7; r=fid>>3; ne=xcd*12+(r%12); by=r/12 (m16);
//     bx=ne%24 (n); z=ne/24 (e)   -> each XCD owns 12 (n,e) B-tiles
//  2: FF2 flat 768:  z=fid&7; r=fid>>3; bx=r%6 (n); by=r/6 (m16)
//     -> each XCD owns one K-slice (B-slice 2.4MB L2-resident)
// ---------------------------------------------------------------------------
__global__ __launch_bounds__(256) void gemm_bt_kernel(
    const u16* __restrict__ A, int lda, long aZ,
    const u16* __restrict__ Bt, int ldb, long bZ,
    int K, int mode, int swz,
    float* __restrict__ outF, u16* __restrict__ outH,
    u16* __restrict__ outH2, u16* __restrict__ outH3,
    int ldc, long cZ,
    const float* __restrict__ biasF, int biasZ,
    const float* __restrict__ src, const float* __restrict__ comb)
{
    __shared__ __align__(16) u16 As[128 * 32];
    __shared__ __align__(16) u16 Bs[128 * 32];
    const int tid = threadIdx.x;
    int bx, by, z;
    if (swz == 2) {
        const int fid = blockIdx.x;
        z = fid & 7; const int r = fid >> 3;
        bx = r % 6; by = r / 6;
    } else if (swz == 1) {
        const int fid = blockIdx.x;
        const int xcd = fid & 7; const int r = fid >> 3;
        const int ne = xcd * 12 + (r % 12);
        by = r / 12; bx = ne % 24; z = ne / 24;
    } else {
        bx = blockIdx.x; by = blockIdx.y; z = blockIdx.z;
    }
    const int m0 = by * 128, n0 = bx * 128;
    const u16* Ab = A + (size_t)z * aZ;
    const u16* Bb = Bt + (size_t)z * bZ;

    const int wave = tid >> 6, lane = tid & 63;
    const int wm = (wave & 1) * 64, wn = (wave >> 1) * 64;
    const int fm = lane & 15;
    const int g  = lane >> 4;

    // staging: wave w covers tile rows [w*32, w*32+32), 2 instrs per operand
    const int lrow = lane >> 2;             // 0..15
    const int lgrp = lane & 3;              // 0..3
    const int cg   = (lgrp ^ ((lrow >> 1) & 3)) * 8;   // swizzled col group
    const int r0   = wave * 32 + lrow;
    const u16* aG0 = Ab + (size_t)(m0 + r0) * lda + cg;
    const u16* aG1 = Ab + (size_t)(m0 + r0 + 16) * lda + cg;
    const u16* bG0 = Bb + (size_t)(n0 + r0) * ldb + cg;
    const u16* bG1 = Bb + (size_t)(n0 + r0 + 16) * ldb + cg;
    u16* aL0 = &As[(wave * 32) * 32];
    u16* aL1 = &As[(wave * 32 + 16) * 32];
    u16* bL0 = &Bs[(wave * 32) * 32];
    u16* bL1 = &Bs[(wave * 32 + 16) * 32];

    // fragment LDS addresses (loop-invariant); read swizzle mirrors store
    const int sw8 = ((fm >> 1) & 3) * 8;
    const u16* pa[4]; const u16* pb[4];
    #pragma unroll
    for (int i = 0; i < 4; i++) {
        pa[i] = &As[(wm + i * 16 + fm) * 32 + ((g * 8) ^ sw8)];
        pb[i] = &Bs[(wn + i * 16 + fm) * 32 + ((g * 8) ^ sw8)];
    }

    f32x4 acc[4][4] = {};

    for (int k0 = 0; k0 < K; k0 += 32) {
        ASYNC16(aG0 + k0, aL0);
        ASYNC16(aG1 + k0, aL1);
        ASYNC16(bG0 + k0, bL0);
        ASYNC16(bG1 + k0, bL1);
        __syncthreads();

        bf16x8 af[4], bf[4];
        #pragma unroll
        for (int i = 0; i < 4; i++) af[i] = *reinterpret_cast<const bf16x8*>(pa[i]);
        #pragma unroll
        for (int j = 0; j < 4; j++) bf[j] = *reinterpret_cast<const bf16x8*>(pb[j]);
        #pragma unroll
        for (int i = 0; i < 4; i++)
            #pragma unroll
            for (int j = 0; j < 4; j++)
                acc[i][j] = MFMA16(af[i], bf[j], acc[i][j]);
        __syncthreads();
    }

    // C/D layout: col = lane&15, row = (lane>>4)*4 + reg   [m89-verified]
    const int cn = lane & 15, cr = (lane >> 4) * 4;

    if (mode == 2) {
        // LDS-repacked epilogue: 4 passes x 32 rows, dwordx4 coalesced stores
        u16* Cs = As;
        #pragma unroll
        for (int i = 0; i < 4; i++) {
            if (i) __syncthreads();
            #pragma unroll
            for (int j = 0; j < 4; j++) {
                const int n = n0 + wn + j * 16 + cn;
                const float bias = biasF[(size_t)z * biasZ + n];
                #pragma unroll
                for (int r = 0; r < 4; r++) {
                    const int m = m0 + wm + i * 16 + cr + r;
                    float y = fmaxf(acc[i][j][r] + bias, 0.f) * comb[m * NE + z];
                    Cs[((wave & 1) * 16 + cr + r) * 128 + wn + j * 16 + cn] = f2us(y);
                }
            }
            __syncthreads();
            const int lr2 = tid >> 3, c2 = (tid & 7) * 16;
            const int m2 = m0 + (lr2 >> 4) * 64 + i * 16 + (lr2 & 15);
            u16* dst = outH + (size_t)m2 * ldc + (size_t)z * cZ + n0 + c2;
            *reinterpret_cast<uint4*>(dst) =
                *reinterpret_cast<const uint4*>(&Cs[lr2 * 128 + c2]);
            *reinterpret_cast<uint4*>(dst + 8) =
                *reinterpret_cast<const uint4*>(&Cs[lr2 * 128 + c2 + 8]);
        }
        return;
    }

    #pragma unroll
    for (int i = 0; i < 4; i++) {
        #pragma unroll
        for (int j = 0; j < 4; j++) {
            const int n = n0 + wn + j * 16 + cn;
            #pragma unroll
            for (int r = 0; r < 4; r++) {
                const int m = m0 + wm + i * 16 + cr + r;
                float y = acc[i][j][r];
                if (mode == 0) {
                    y += biasF[n];
                    int which = (n >= 1536) ? 2 : (n >= 768 ? 1 : 0);
                    int nn = n - which * 768;
                    int bb = m >> 10, t = m & 1023;
                    int hh = nn >> 6, d = nn & 63;
                    if (which == 0)
                        outH[(((size_t)(bb * HH + hh) * TT + t) << 6) + d] = f2us(y);
                    else if (which == 1)
                        outH2[(((size_t)(bb * HH + hh) * TT + t) << 6) + d] = f2us(y);
                    else
                        outH3[(((size_t)(bb * HH + hh) * HD + d) << 10) + t] = f2us(y);
                } else {
                    float* base = (z < 4) ? (outF + (size_t)z * cZ)
                                : (z < 7) ? ((float*)outH + (size_t)(z - 4) * cZ)
                                          : (float*)outH2;
                    base[(size_t)m * ldc + n] = y;
                }
            }
        }
    }
}

// ---------------------------------------------------------------------------
// MFMA attention. Block = (qt 32 rows, b*12+h). 4 waves.
// Phase 1: S[32][1024] in accumulators (wave w covers cols w*256..+256).
// zscore is scale-invariant: a = gamma/(std_ddof1(S)+EPS_Z/0.125); shift
// cancels in softmax; cm = max(a*S) for stability.
// Phase 2: P bf16 in LDS; O = P*V via MFMA (V pre-transposed [B,H,64,T]).
// ---------------------------------------------------------------------------
#define PSTR 1032  // u16 stride: byte stride 2064 (16B aligned), dw 516 ≡ 4 mod 8 -> conflict-free b128
__global__ __launch_bounds__(256, 2) void attn_mfma_kernel(
    const u16* __restrict__ Qh, const u16* __restrict__ Kh,
    const u16* __restrict__ VT, const float* __restrict__ gamma_p,
    u16* __restrict__ attn_out)
{
    __shared__ __align__(16) u16 P[32 * PSTR];
    __shared__ float wred[4][32][4];
    __shared__ float dred[4][32];
    __shared__ float aArr[32], cmArr[32], dinvArr[32];

    const int qt = blockIdx.x, bh = blockIdx.y;
    const int b = bh / HH, h = bh - b * HH;
    const int tid = threadIdx.x, wave = tid >> 6, lane = tid & 63;
    const int g = lane >> 4, fm = lane & 15;
    const float gamma = gamma_p[0];
    const int m0 = qt * 32;
    const u16* Qp = Qh + (size_t)bh * TT * HD;
    const u16* Kp = Kh + (size_t)bh * TT * HD;
    const u16* Vp = VT + (size_t)bh * HD * TT;

    bf16x8 af[2][2];
    #pragma unroll
    for (int mi = 0; mi < 2; mi++)
        #pragma unroll
        for (int ks = 0; ks < 2; ks++)
            af[mi][ks] = *reinterpret_cast<const bf16x8*>(
                Qp + (size_t)(m0 + mi * 16 + fm) * HD + ks * 32 + g * 8);

    const int n0w = wave * 256;
    f32x4 acc[16][2] = {};
    #pragma unroll
    for (int nj = 0; nj < 16; nj++) {
        const u16* kp = Kp + (size_t)(n0w + nj * 16 + fm) * HD + g * 8;
        bf16x8 b0 = *reinterpret_cast<const bf16x8*>(kp);
        bf16x8 b1 = *reinterpret_cast<const bf16x8*>(kp + 32);
        acc[nj][0] = MFMA16(af[0][0], b0, acc[nj][0]);
        acc[nj][0] = MFMA16(af[0][1], b1, acc[nj][0]);
        acc[nj][1] = MFMA16(af[1][0], b0, acc[nj][1]);
        acc[nj][1] = MFMA16(af[1][1], b1, acc[nj][1]);
    }

    #pragma unroll
    for (int mi = 0; mi < 2; mi++) {
        #pragma unroll
        for (int r = 0; r < 4; r++) {
            float s1 = 0.f, s2 = 0.f, mx = -3.4e38f, mn = 3.4e38f;
            #pragma unroll
            for (int nj = 0; nj < 16; nj++) {
                float v = acc[nj][mi][r];
                s1 += v; s2 = fmaf(v, v, s2);
                mx = fmaxf(mx, v); mn = fminf(mn, v);
            }
            #pragma unroll
            for (int msk = 1; msk < 16; msk <<= 1) {
                s1 += __shfl_xor(s1, msk);
                s2 += __shfl_xor(s2, msk);
                mx = fmaxf(mx, __shfl_xor(mx, msk));
                mn = fminf(mn, __shfl_xor(mn, msk));
            }
            if (fm == 0) {
                int row = mi * 16 + g * 4 + r;
                wred[wave][row][0] = s1; wred[wave][row][1] = s2;
                wred[wave][row][2] = mx; wred[wave][row][3] = mn;
            }
        }
    }
    __syncthreads();
    if (tid < 32) {
        float s1 = 0.f, s2 = 0.f, mx = -3.4e38f, mn = 3.4e38f;
        #pragma unroll
        for (int w = 0; w < 4; w++) {
            s1 += wred[w][tid][0]; s2 += wred[w][tid][1];
            mx = fmaxf(mx, wred[w][tid][2]); mn = fminf(mn, wred[w][tid][3]);
        }
        float var = (s2 - s1 * s1 * (1.f / TT)) * (1.f / (TT - 1));
        var = fmaxf(var, 0.f);
        float a = gamma / (sqrtf(var) + 8e-5f);
        aArr[tid] = a;
        cmArr[tid] = (a >= 0.f) ? a * mx : a * mn;
    }
    __syncthreads();

    #pragma unroll
    for (int mi = 0; mi < 2; mi++) {
        #pragma unroll
        for (int r = 0; r < 4; r++) {
            const int row = mi * 16 + g * 4 + r;
            const float a = aArr[row], cm = cmArr[row];
            float dp = 0.f;
            #pragma unroll
            for (int nj = 0; nj < 16; nj++) {
                float p = __expf(fmaf(a, acc[nj][mi][r], -cm));
                u16 pb = f2us(p);
                dp += us2f(pb);
                P[row * PSTR + n0w + nj * 16 + fm] = pb;
            }
            #pragma unroll
            for (int msk = 1; msk < 16; msk <<= 1) dp += __shfl_xor(dp, msk);
            if (fm == 0) dred[wave][row] = dp;
        }
    }
    __syncthreads();
    if (tid < 32)
        dinvArr[tid] = 1.f / (dred[0][tid] + dred[1][tid] + dred[2][tid] + dred[3][tid]);
    __syncthreads();

    f32x4 oacc[2] = {};
    #pragma unroll 4
    for (int ks = 0; ks < 32; ks++) {
        bf16x8 bv = *reinterpret_cast<const bf16x8*>(
            Vp + (size_t)(wave * 16 + fm) * TT + ks * 32 + g * 8);
        bf16x8 a0 = *reinterpret_cast<const bf16x8*>(&P[(size_t)fm * PSTR + ks * 32 + g * 8]);
        bf16x8 a1 = *reinterpret_cast<const bf16x8*>(&P[(size_t)(16 + fm) * PSTR + ks * 32 + g * 8]);
        oacc[0] = MFMA16(a0, bv, oacc[0]);
        oacc[1] = MFMA16(a1, bv, oacc[1]);
    }
    #pragma unroll
    for (int mi = 0; mi < 2; mi++) {
        #pragma unroll
        for (int r = 0; r < 4; r++) {
            int row = mi * 16 + g * 4 + r;
            int t = m0 + row;
            attn_out[((size_t)(b * TT + t)) * DD + h * HD + wave * 16 + fm] =
                f2us(oacc[mi][r] * dinvArr[row]);
        }
    }
}

// ---------------------------------------------------------------------------
// LN1 fused: r1 = p0+p1+p2+p3 (Wo split-K partials) + src + bo; layernorm ->
// x fp32 + xh bf16.
// ---------------------------------------------------------------------------
__global__ __launch_bounds__(256) void ln1_kernel(
    const float* __restrict__ p0, const float* __restrict__ p1,
    const float* __restrict__ p2, const float* __restrict__ p3,
    const float* __restrict__ src, const float* __restrict__ bo,
    const float* __restrict__ g, const float* __restrict__ bta,
    float* __restrict__ outF, u16* __restrict__ outH)
{
    const int row = blockIdx.x, tid = threadIdx.x;
    __shared__ float red[256];
    const size_t base = (size_t)row * DD;
    float v[3];
    #pragma unroll
    for (int i = 0; i < 3; i++) {
        int c = tid + i * 256;
        v[i] = p0[base + c] + p1[base + c] + p2[base + c] + p3[base + c]
             + src[base + c] + bo[c];
    }
    float s = v[0] + v[1] + v[2];
    red[tid] = s; __syncthreads();
    #pragma unroll
    for (int o = 128; o > 0; o >>= 1) { if (tid < o) red[tid] += red[tid + o]; __syncthreads(); }
    const float mean = red[0] * (1.f / 768.f);
    __syncthreads();
    float qv = 0.f;
    #pragma unroll
    for (int i = 0; i < 3; i++) { float d = v[i] - mean; qv += d * d; }
    red[tid] = qv; __syncthreads();
    #pragma unroll
    for (int o = 128; o > 0; o >>= 1) { if (tid < o) red[tid] += red[tid + o]; __syncthreads(); }
    const float var = red[0] * (1.f / 768.f);
    const float rs = rsqrtf(var + 1e-5f);
    #pragma unroll
    for (int i = 0; i < 3; i++) {
        int c = tid + i * 256;
        float o = (v[i] - mean) * rs * g[c] + bta[c];
        outF[base + c] = o;
        outH[base + c] = f2us(o);
    }
}

// ---------------------------------------------------------------------------
// LN2: t = x + sum of 8 split-K partials + sum_e comb[m,e]*b2[e,c]; layernorm.
// p7 may alias outF (d_out): all reads precede the first barrier, rows are
// block-disjoint, so the late store is safe.
// ---------------------------------------------------------------------------
__global__ __launch_bounds__(256) void ln2_kernel(
    const float* __restrict__ x,
    const float* __restrict__ p0, const float* __restrict__ p1,
    const float* __restrict__ p2, const float* __restrict__ p3,
    const float* __restrict__ p4, const float* __restrict__ p5,
    const float* __restrict__ p6, const float* __restrict__ p7,
    const float* __restrict__ comb, const float* __restrict__ b2,
    const float* __restrict__ g, const float* __restrict__ bta,
    float* __restrict__ outF)
{
    const int row = blockIdx.x, tid = threadIdx.x;
    __shared__ float red[256];
    const size_t base = (size_t)row * DD;
    const float c0 = comb[row * NE + 0], c1 = comb[row * NE + 1];
    const float c2 = comb[row * NE + 2], c3 = comb[row * NE + 3];
    float v[3];
    #pragma unroll
    for (int i = 0; i < 3; i++) {
        int c = tid + i * 256;
        float t = x[base + c];
        t += p0[base + c] + p1[base + c] + p2[base + c] + p3[base + c];
        t += p4[base + c] + p5[base + c] + p6[base + c] + p7[base + c];
        t = fmaf(c0, b2[c], t);
        t = fmaf(c1, b2[DD + c], t);
        t = fmaf(c2, b2[2 * DD + c], t);
        t = fmaf(c3, b2[3 * DD + c], t);
        v[i] = t;
    }
    float s = v[0] + v[1] + v[2];
    red[tid] = s; __syncthreads();
    #pragma unroll
    for (int o = 128; o > 0; o >>= 1) { if (tid < o) red[tid] += red[tid + o]; __syncthreads(); }
    const float mean = red[0] * (1.f / 768.f);
    __syncthreads();
    float qv = 0.f;
    #pragma unroll
    for (int i = 0; i < 3; i++) { float d = v[i] - mean; qv += d * d; }
    red[tid] = qv; __syncthreads();
    #pragma unroll
    for (int o = 128; o > 0; o >>= 1) { if (tid < o) red[tid] += red[tid + o]; __syncthreads(); }
    const float var = red[0] * (1.f / 768.f);
    const float rs = rsqrtf(var + 1e-5f);
    #pragma unroll
    for (int i = 0; i < 3; i++) {
        int c = tid + i * 256;
        outF[base + c] = (v[i] - mean) * rs * g[c] + bta[c];
    }
}

// ---------------------------------------------------------------------------
// Gate: one wave per token. softmax over E=4, top-2 -> combine weights.
// ---------------------------------------------------------------------------
__global__ __launch_bounds__(256) void gate_kernel(
    const float* __restrict__ x, const float* __restrict__ Wg,
    const float* __restrict__ bg, float* __restrict__ comb)
{
    const int wid = threadIdx.x >> 6, lane = threadIdx.x & 63;
    const int t = blockIdx.x * 4 + wid;
    const float* xr = x + (size_t)t * DD;
    float g[NE];
    #pragma unroll
    for (int e = 0; e < NE; e++) {
        float p = 0.f;
        for (int d = lane; d < DD; d += 64) p += xr[d] * Wg[e * DD + d];
        #pragma unroll
        for (int off = 32; off > 0; off >>= 1) p += __shfl_down(p, off, 64);
        g[e] = p;
    }
    if (lane == 0) {
        float m = -1e30f;
        #pragma unroll
        for (int e = 0; e < NE; e++) { g[e] += bg[e]; m = fmaxf(m, g[e]); }
        float ex[NE], s = 0.f;
        #pragma unroll
        for (int e = 0; e < NE; e++) { ex[e] = __expf(g[e] - m); s += ex[e]; }
        #pragma unroll
        for (int e = 0; e < NE; e++) ex[e] /= s;
        int e1 = 0;
        #pragma unroll
        for (int e = 1; e < NE; e++) if (ex[e] > ex[e1]) e1 = e;
        int e2 = -1;
        #pragma unroll
        for (int e = 0; e < NE; e++) if (e != e1 && (e2 < 0 || ex[e] > ex[e2])) e2 = e;
        float c[NE] = {0.f, 0.f, 0.f, 0.f};
        c[e1] = ex[e1]; c[e2] = ex[e2];
        #pragma unroll
        for (int e = 0; e < NE; e++) comb[(size_t)t * NE + e] = c[e];
    }
}

extern "C" void kernel_launch(void* const* d_in, const int* in_sizes, int n_in,
                              void* d_out, int out_size, void* d_ws, size_t ws_size,
                              hipStream_t stream)
{
    const float* src  = (const float*)d_in[0];
    const float* Wq   = (const float*)d_in[2];  const float* bq = (const float*)d_in[3];
    const float* Wk   = (const float*)d_in[4];  const float* bk = (const float*)d_in[5];
    const float* Wv   = (const float*)d_in[6];  const float* bv = (const float*)d_in[7];
    const float* Wo   = (const float*)d_in[8];  const float* bo = (const float*)d_in[9];
    const float* gam  = (const float*)d_in[10];
    const float* ln1g = (const float*)d_in[11]; const float* ln1b = (const float*)d_in[12];
    const float* ln2g = (const float*)d_in[13]; const float* ln2b = (const float*)d_in[14];
    const float* Wg   = (const float*)d_in[15]; const float* bg = (const float*)d_in[16];
    const float* W1   = (const float*)d_in[17]; const float* b1 = (const float*)d_in[18];
    const float* W2   = (const float*)d_in[19]; const float* b2 = (const float*)d_in[20];
    (void)ws_size; (void)in_sizes; (void)n_in; (void)out_size;

    char* ws = (char*)d_ws;
    // persistent regions
    u16*   W1T  = (u16*)(ws);                              // 18,874,368 B (dead after FF1 -> FF2 partials 4..6)
    u16*   W2T  = (u16*)(ws + 18874368);                   // 18,874,368 B
    u16*   hb   = (u16*)(ws + 37748736);                   // 50,331,648 B
    float* x    = (float*)(ws + 88080384);                 //  6,291,456 B
    u16*   xh   = (u16*)(ws + 94371840);                   //  3,145,728 B
    float* ffp  = (float*)(ws + 97517568);                 // 25,165,824 B (Wo partials, then FF2 partials 0..3)
    float* comb = (float*)(ws + 122683392);                //     32,768 B
    float* bqkv = (float*)(ws + 122716160);                //      9,216 B
    // aliases inside hb region (all dead before FF1 writes hb)
    char* H = ws + 37748736;
    u16*   Qh     = (u16*)(H);                             //  3,145,728 B
    u16*   Kh     = (u16*)(H + 3145728);                   //  3,145,728 B
    u16*   VTh    = (u16*)(H + 6291456);                   //  3,145,728 B
    u16*   src_h  = (u16*)(H + 9437184);                   //  3,145,728 B
    u16*   attn_h = (u16*)(H + 12582912);                  //  3,145,728 B
    u16*   WqkvH  = (u16*)(H + 15728640);                  //  3,538,944 B
    u16*   WoH    = (u16*)(H + 19267584);                  //  1,179,648 B
    // FF2 split-K partials 4..6 live in the (dead) W1T region; 7 in d_out.
    float* ffpB = (float*)ws;
    const long PZ = (long)NTOK * DD;

    const int DW = DD * DD;  // 589824

    // ---- weight/activation conversions ----
    convert_kernel<<<(NTOK * DD / 8 + 255) / 256, 256, 0, stream>>>(src, src_h, NTOK * DD / 8);
    convert_kernel<<<(DW / 8 + 255) / 256, 256, 0, stream>>>(Wq, WqkvH, DW / 8);
    convert_kernel<<<(DW / 8 + 255) / 256, 256, 0, stream>>>(Wk, WqkvH + DW, DW / 8);
    convert_kernel<<<(DW / 8 + 255) / 256, 256, 0, stream>>>(Wv, WqkvH + 2 * DW, DW / 8);
    convert_kernel<<<(DW / 8 + 255) / 256, 256, 0, stream>>>(Wo, WoH, DW / 8);
    hipMemcpyAsync(bqkv, bq, DD * 4, hipMemcpyDeviceToDevice, stream);
    hipMemcpyAsync(bqkv + DD, bk, DD * 4, hipMemcpyDeviceToDevice, stream);
    hipMemcpyAsync(bqkv + 2 * DD, bv, DD * 4, hipMemcpyDeviceToDevice, stream);
    // W1[e]: [768,3072] -> [3072,768] per expert
    transpose_convert_kernel<<<dim3(FFD / 32, DD / 32, NE), 256, 0, stream>>>(
        W1, W1T, FFD, DD, (long)DD * FFD, (long)FFD * DD);
    // W2[e]: [3072,768] -> W2T[n][e*3072+k], row stride 12288
    transpose_convert_kernel<<<dim3(DD / 32, FFD / 32, NE), 256, 0, stream>>>(
        W2, W2T, DD, NE * FFD, (long)FFD * DD, (long)FFD);

    // ---- QKV (batched, N=2304) -> bf16 Q,K [B,H,T,64], V^T [B,H,64,T] ----
    gemm_bt_kernel<<<dim3(2304 / 128, NTOK / 128, 1), 256, 0, stream>>>(
        src_h, DD, 0, WqkvH, DD, 0, DD, 0, 0,
        nullptr, Qh, Kh, VTh, 0, 0, bqkv, 0, nullptr, nullptr);

    // ---- attention (MFMA) ----
    attn_mfma_kernel<<<dim3(TT / 32, BB * HH), 256, 0, stream>>>(
        Qh, Kh, VTh, gam, attn_h);

    // ---- Wo projection split-K x4 -> fp32 partials in ffp ----
    gemm_bt_kernel<<<dim3(DD / 128, NTOK / 128, 4), 256, 0, stream>>>(
        attn_h, DD, 192L, WoH, DD, 192L, 192, 3, 0,
        ffp, nullptr, nullptr, nullptr, DD, PZ, nullptr, 0, nullptr, nullptr);

    // ---- LN1 (sums Wo partials + residual + bias inline) ----
    ln1_kernel<<<NTOK, 256, 0, stream>>>(
        ffp, ffp + PZ, ffp + 2 * PZ, ffp + 3 * PZ, src, bo,
        ln1g, ln1b, x, xh);

    // ---- gate ----
    gate_kernel<<<NTOK / 4, 256, 0, stream>>>(x, Wg, bg, comb);

    // ---- FF1 (XCD-swizzled flat grid: each XCD owns 12 (n,e) B-tiles) ----
    gemm_bt_kernel<<<dim3(1536, 1, 1), 256, 0, stream>>>(
        xh, DD, 0, W1T, DD, (long)FFD * DD, DD, 2, 1,
        nullptr, hb, nullptr, nullptr, NE * FFD, FFD, b1, FFD, nullptr, comb);

    // ---- FF2 merged-K (K=12288) split-K x8, XCD-swizzled (each XCD owns one
    //      K-slice; W2T slice L2-resident) -> 8 fp32 partial slabs ----
    gemm_bt_kernel<<<dim3(768, 1, 1), 256, 0, stream>>>(
        hb, NE * FFD, 1536L, W2T, NE * FFD, 1536L, 1536, 3, 2,
        ffp, (u16*)ffpB, (u16*)d_out, nullptr, DD, PZ, nullptr, 0, nullptr, nullptr);

    // ---- LN2 (x + 8 partials + comb*b2, then layernorm) ----
    ln2_kernel<<<NTOK, 256, 0, stream>>>(
        x, ffp, ffp + PZ, ffp + 2 * PZ, ffp + 3 * PZ,
        ffpB, ffpB + PZ, ffpB + 2 * PZ, (float*)d_out,
        comb, b2, ln2g, ln2b, (float*)d_out);
}